// Round 13
// baseline (384.898 us; speedup 1.0000x reference)
//
#include <hip/hip_runtime.h>

#define NB 16
#define NP 2048
#define HD 128
#define LDP 136   // padded LDS row (bf16 elems)
#define JSEG 4    // j-range split for knn_big (4 -> 1024 blocks = 4/CU = full 32 waves/CU)

typedef __bf16 bf16_t;
typedef bf16_t bf16x8 __attribute__((ext_vector_type(8)));
typedef bf16_t bf16x4 __attribute__((ext_vector_type(4)));
typedef float  f32x4  __attribute__((ext_vector_type(4)));

// ---------------- packed-key top-8 machinery ----------------
__device__ __forceinline__ unsigned pk_max(float k, unsigned jrev) {
  unsigned u = __float_as_uint(k);
  unsigned s = u ^ (unsigned)(((int)u >> 31) | 0x80000000);
  return (s & 0xFFFFF800u) | jrev;
}
__device__ __forceinline__ unsigned pk_min(float k, unsigned j) {
  unsigned u = __float_as_uint(k);
  unsigned s = u ^ (unsigned)(((int)u >> 31) | 0x80000000);
  return (s & 0xFFFFF800u) | j;
}

#define T8_DECL_MAX(p) unsigned p##0=0u,p##1=0u,p##2=0u,p##3=0u,p##4=0u,p##5=0u,p##6=0u,p##7=0u
#define T8_STEP_MAX(b,cc) { unsigned t_ = ((b)<(cc)?(b):(cc)); (b) = ((b)>(cc)?(b):(cc)); (cc) = t_; }
#define T8_INS_MAX(p,c) { unsigned cc_=(c); \
  T8_STEP_MAX(p##0,cc_) T8_STEP_MAX(p##1,cc_) T8_STEP_MAX(p##2,cc_) T8_STEP_MAX(p##3,cc_) \
  T8_STEP_MAX(p##4,cc_) T8_STEP_MAX(p##5,cc_) T8_STEP_MAX(p##6,cc_) T8_STEP_MAX(p##7,cc_) }
#define T8_GINS_MAX(p,c) { unsigned cg_=(c); if (cg_ > p##7) { T8_INS_MAX(p, cg_) } }

#define T8_DECL_MIN(p) unsigned p##0=0xFFFFFFFFu,p##1=0xFFFFFFFFu,p##2=0xFFFFFFFFu,p##3=0xFFFFFFFFu,p##4=0xFFFFFFFFu,p##5=0xFFFFFFFFu,p##6=0xFFFFFFFFu,p##7=0xFFFFFFFFu
#define T8_STEP_MIN(b,cc) { unsigned t_ = ((b)>(cc)?(b):(cc)); (b) = ((b)<(cc)?(b):(cc)); (cc) = t_; }
#define T8_INS_MIN(p,c) { unsigned cc_=(c); \
  T8_STEP_MIN(p##0,cc_) T8_STEP_MIN(p##1,cc_) T8_STEP_MIN(p##2,cc_) T8_STEP_MIN(p##3,cc_) \
  T8_STEP_MIN(p##4,cc_) T8_STEP_MIN(p##5,cc_) T8_STEP_MIN(p##6,cc_) T8_STEP_MIN(p##7,cc_) }
#define T8_GINS_MIN(p,c) { unsigned cg_=(c); if (cg_ < p##7) { T8_INS_MIN(p, cg_) } }

// ---- batched bitonic top-8 update (exact, branchless; faiss-style) ----
#define CMPX_DESC(a,b) { unsigned h_=((a)>(b)?(a):(b)); unsigned l_=((a)<(b)?(a):(b)); (a)=h_; (b)=l_; }
#define CMPX_ASC(a,b)  { unsigned l_=((a)<(b)?(a):(b)); unsigned h_=((a)>(b)?(a):(b)); (a)=l_; (b)=h_; }

#define T8_B4_MAX(p, d0,d1,d2,d3) { \
  unsigned x0_=(d0), x1_=(d1), x2_=(d2), x3_=(d3); \
  CMPX_DESC(x0_,x1_) CMPX_DESC(x2_,x3_) CMPX_DESC(x0_,x2_) CMPX_DESC(x1_,x3_) CMPX_DESC(x1_,x2_) \
  p##4 = p##4 > x3_ ? p##4 : x3_; \
  p##5 = p##5 > x2_ ? p##5 : x2_; \
  p##6 = p##6 > x1_ ? p##6 : x1_; \
  p##7 = p##7 > x0_ ? p##7 : x0_; \
  CMPX_DESC(p##0,p##4) CMPX_DESC(p##1,p##5) CMPX_DESC(p##2,p##6) CMPX_DESC(p##3,p##7) \
  CMPX_DESC(p##0,p##2) CMPX_DESC(p##1,p##3) CMPX_DESC(p##4,p##6) CMPX_DESC(p##5,p##7) \
  CMPX_DESC(p##0,p##1) CMPX_DESC(p##2,p##3) CMPX_DESC(p##4,p##5) CMPX_DESC(p##6,p##7) }

#define T8_B4_MIN(p, d0,d1,d2,d3) { \
  unsigned x0_=(d0), x1_=(d1), x2_=(d2), x3_=(d3); \
  CMPX_ASC(x0_,x1_) CMPX_ASC(x2_,x3_) CMPX_ASC(x0_,x2_) CMPX_ASC(x1_,x3_) CMPX_ASC(x1_,x2_) \
  p##4 = p##4 < x3_ ? p##4 : x3_; \
  p##5 = p##5 < x2_ ? p##5 : x2_; \
  p##6 = p##6 < x1_ ? p##6 : x1_; \
  p##7 = p##7 < x0_ ? p##7 : x0_; \
  CMPX_ASC(p##0,p##4) CMPX_ASC(p##1,p##5) CMPX_ASC(p##2,p##6) CMPX_ASC(p##3,p##7) \
  CMPX_ASC(p##0,p##2) CMPX_ASC(p##1,p##3) CMPX_ASC(p##4,p##6) CMPX_ASC(p##5,p##7) \
  CMPX_ASC(p##0,p##1) CMPX_ASC(p##2,p##3) CMPX_ASC(p##4,p##5) CMPX_ASC(p##6,p##7) }

// ---- shuffle butterfly merge: merge own sorted-8(desc) with lane^mask partner's ----
#define T8_SHMERGE_MAX(p, mask) { \
  unsigned o_; \
  o_ = (unsigned)__shfl_xor((int)p##7, mask); p##0 = p##0 > o_ ? p##0 : o_; \
  o_ = (unsigned)__shfl_xor((int)p##6, mask); p##1 = p##1 > o_ ? p##1 : o_; \
  o_ = (unsigned)__shfl_xor((int)p##5, mask); p##2 = p##2 > o_ ? p##2 : o_; \
  o_ = (unsigned)__shfl_xor((int)p##4, mask); p##3 = p##3 > o_ ? p##3 : o_; \
  o_ = (unsigned)__shfl_xor((int)p##3, mask); p##4 = p##4 > o_ ? p##4 : o_; \
  o_ = (unsigned)__shfl_xor((int)p##2, mask); p##5 = p##5 > o_ ? p##5 : o_; \
  o_ = (unsigned)__shfl_xor((int)p##1, mask); p##6 = p##6 > o_ ? p##6 : o_; \
  o_ = (unsigned)__shfl_xor((int)p##0, mask); p##7 = p##7 > o_ ? p##7 : o_; \
  CMPX_DESC(p##0,p##4) CMPX_DESC(p##1,p##5) CMPX_DESC(p##2,p##6) CMPX_DESC(p##3,p##7) \
  CMPX_DESC(p##0,p##2) CMPX_DESC(p##1,p##3) CMPX_DESC(p##4,p##6) CMPX_DESC(p##5,p##7) \
  CMPX_DESC(p##0,p##1) CMPX_DESC(p##2,p##3) CMPX_DESC(p##4,p##5) CMPX_DESC(p##6,p##7) }

// ---------------- weight prep ----------------
__global__ __launch_bounds__(256) void wprep_kernel(
    const float* __restrict__ c1W2, const float* __restrict__ c2W1, const float* __restrict__ c2W2,
    const float* __restrict__ c3W1, const float* __restrict__ c3W2,
    bf16_t* __restrict__ W2T1, bf16_t* __restrict__ WpT2, bf16_t* __restrict__ WqT2,
    bf16_t* __restrict__ W2T2, bf16_t* __restrict__ WpT3, bf16_t* __restrict__ WqT3,
    bf16_t* __restrict__ W2T3)
{
  int tid = blockIdx.x * 256 + threadIdx.x;     // < 7*16384
  int m = tid >> 14, e = tid & 16383;
  int r = e >> 7, c = e & 127;
  switch (m) {
    case 0: W2T1[r*128+c] = (bf16_t)c1W2[c*128+r]; break;
    case 1: WpT2[r*128+c] = (bf16_t)(c2W1[c*128+r] - c2W1[(128+c)*128+r]); break;
    case 2: WqT2[r*128+c] = (bf16_t)c2W1[(128+c)*128+r]; break;
    case 3: W2T2[r*128+c] = (bf16_t)c2W2[c*128+r]; break;
    case 4: WpT3[r*128+c] = (bf16_t)(c3W1[c*128+r] - c3W1[(128+c)*128+r]); break;
    case 5: WqT3[r*128+c] = (bf16_t)c3W1[(128+c)*128+r]; break;
    case 6: W2T3[r*128+c] = (bf16_t)c3W2[c*128+r]; break;
  }
}

// ---------------- layer-1 P/Q (bf16 out) ----------------
__global__ __launch_bounds__(256) void pq1_kernel(
    const float* __restrict__ x, const float* __restrict__ W1, const float* __restrict__ b1,
    bf16_t* __restrict__ P, bf16_t* __restrict__ Q)
{
  int tid = blockIdx.x * 256 + threadIdx.x;     // < 32768*32
  int row = tid >> 5, c0 = (tid & 31) * 4;
  float x0 = x[row*3+0], x1 = x[row*3+1], x2 = x[row*3+2];
  bf16x4 pv, qv;
#pragma unroll
  for (int u = 0; u < 4; ++u) {
    int c = c0 + u;
    float wq0 = W1[3*128+c], wq1 = W1[4*128+c], wq2 = W1[5*128+c];
    float wp0 = W1[0*128+c]-wq0, wp1 = W1[1*128+c]-wq1, wp2 = W1[2*128+c]-wq2;
    pv[u] = (bf16_t)(x0*wp0 + x1*wp1 + x2*wp2 + b1[c]);
    qv[u] = (bf16_t)(x0*wq0 + x1*wq1 + x2*wq2);
  }
  *(bf16x4*)&P[(size_t)row*HD + c0] = pv;
  *(bf16x4*)&Q[(size_t)row*HD + c0] = qv;
}

// ---------------- kNN layer 1 (32 rows/block, 8 partitions, batched bitonic top-8) ----------------
__global__ __launch_bounds__(256) void knn1_kernel(const float* __restrict__ x, int* __restrict__ idxo)
{
  __shared__ __align__(16) float4 pts[NP];      // 32 KB: (x, y, z, |x|^2)
  __shared__ unsigned mrg[32 * 64];             // 8 KB merge scratch (packed keys)
  const int b = blockIdx.y, i0 = blockIdx.x * 32;
  const int t = threadIdx.x;
  const float* __restrict__ xb = x + (size_t)b * NP * 3;
  for (int u = t; u < NP; u += 256) {
    float a0 = xb[u*3+0], a1 = xb[u*3+1], a2 = xb[u*3+2];
    pts[u] = make_float4(a0, a1, a2, a0*a0 + a1*a1 + a2*a2);
  }
  __syncthreads();
  const int selr = t >> 3, selp = t & 7;        // 32 rows x 8 partitions
  const float4 pi = pts[i0 + selr];
  T8_DECL_MIN(L);
#pragma unroll 2
  for (int jj = 0; jj < NP / 32; ++jj) {
    const int jb = jj * 32 + selp;
    float4 p0 = pts[jb];
    float4 p1 = pts[jb + 8];
    float4 p2 = pts[jb + 16];
    float4 p3 = pts[jb + 24];
    float k0 = p0.w - 2.0f * (p0.x*pi.x + p0.y*pi.y + p0.z*pi.z);
    float k1 = p1.w - 2.0f * (p1.x*pi.x + p1.y*pi.y + p1.z*pi.z);
    float k2 = p2.w - 2.0f * (p2.x*pi.x + p2.y*pi.y + p2.z*pi.z);
    float k3 = p3.w - 2.0f * (p3.x*pi.x + p3.y*pi.y + p3.z*pi.z);
    T8_B4_MIN(L, pk_min(k0, (unsigned)jb), pk_min(k1, (unsigned)(jb+8)),
                 pk_min(k2, (unsigned)(jb+16)), pk_min(k3, (unsigned)(jb+24)));
  }
  {
    unsigned* e = &mrg[selr*64 + selp*8];
    e[0]=L0; e[1]=L1; e[2]=L2; e[3]=L3; e[4]=L4; e[5]=L5; e[6]=L6; e[7]=L7;
  }
  __syncthreads();
  if (t < 32) {
    T8_DECL_MIN(F);
    const unsigned* q = &mrg[t*64];
#pragma unroll
    for (int m = 0; m < 64; ++m) { unsigned v = q[m]; T8_GINS_MIN(F, v); }
    int* o = idxo + ((size_t)b*NP + i0 + t) * 8;
    o[0] = (int)(F0 & 0x7FFu); o[1] = (int)(F1 & 0x7FFu);
    o[2] = (int)(F2 & 0x7FFu); o[3] = (int)(F3 & 0x7FFu);
    o[4] = (int)(F4 & 0x7FFu); o[5] = (int)(F5 & 0x7FFu);
    o[6] = (int)(F6 & 0x7FFu); o[7] = (int)(F7 & 0x7FFu);
  }
}

// ---------------- bf16 row norms ----------------
__global__ __launch_bounds__(256) void prep_sq_kernel(const bf16_t* __restrict__ X, float* __restrict__ sqg)
{
  int r = blockIdx.x * 256 + threadIdx.x;       // < 32768
  const bf16_t* row = X + (size_t)r * HD;
  float s = 0.f;
#pragma unroll
  for (int c = 0; c < HD; c += 8) {
    bf16x8 v = *(const bf16x8*)&row[c];
#pragma unroll
    for (int q = 0; q < 8; ++q) { float f = (float)v[q]; s += f * f; }
  }
  sqg[r] = s;
}

// ---------------- P/Q GEMM for layers 2/3 (bf16 out) ----------------
__global__ __launch_bounds__(256) void pq_gemm_kernel(
    const bf16_t* __restrict__ X, const bf16_t* __restrict__ WpT, const bf16_t* __restrict__ WqT,
    const float* __restrict__ b1, bf16_t* __restrict__ P, bf16_t* __restrict__ Q)
{
  __shared__ __align__(16) bf16_t At[128 * LDP];
  const int r0 = blockIdx.x * 128;
  const bool isP = (blockIdx.y == 0);
  const bf16_t* __restrict__ WT = isP ? WpT : WqT;
  bf16_t* __restrict__ Out = isP ? P : Q;
  const int t = threadIdx.x;
  for (int u = t; u < 2048; u += 256) {
    int r = u >> 4, c = (u & 15) * 8;
    *(bf16x8*)&At[r*LDP + c] = *(const bf16x8*)&X[(size_t)(r0 + r)*HD + c];
  }
  __syncthreads();
  const int lane = t & 63, w = t >> 6, quad = lane >> 4, l16 = lane & 15;
  f32x4 acc[2][8];
  f32x4 z = {0.f, 0.f, 0.f, 0.f};
#pragma unroll
  for (int rt = 0; rt < 2; ++rt)
#pragma unroll
    for (int ct = 0; ct < 8; ++ct) acc[rt][ct] = z;
#pragma unroll
  for (int ks = 0; ks < 4; ++ks) {
    const int kk = ks*32 + quad*8;
    bf16x8 a0 = *(const bf16x8*)&At[(w*32 + l16)*LDP + kk];
    bf16x8 a1 = *(const bf16x8*)&At[(w*32 + 16 + l16)*LDP + kk];
#pragma unroll
    for (int ct = 0; ct < 8; ++ct) {
      bf16x8 bb = *(const bf16x8*)&WT[(ct*16 + l16)*HD + kk];
      acc[0][ct] = __builtin_amdgcn_mfma_f32_16x16x32_bf16(a0, bb, acc[0][ct], 0, 0, 0);
      acc[1][ct] = __builtin_amdgcn_mfma_f32_16x16x32_bf16(a1, bb, acc[1][ct], 0, 0, 0);
    }
  }
#pragma unroll
  for (int rt = 0; rt < 2; ++rt)
#pragma unroll
    for (int ct = 0; ct < 8; ++ct) {
      float bv = isP ? b1[ct*16 + l16] : 0.f;
#pragma unroll
      for (int r = 0; r < 4; ++r) {
        int row = w*32 + rt*16 + quad*4 + r;
        Out[(size_t)(r0 + row)*HD + ct*16 + l16] = (bf16_t)(acc[rt][ct][r] + bv);
      }
    }
}

// ---------------- fused Gram(MFMA) + bitonic top-8; 8 waves share B-tile; shfl merge ----------------
// 512 threads = 8 waves x 16 rows = 128 i-rows/block. JSEG=4 -> 1024 blocks = 4/CU
// (full 32 waves/CU; LDS 4x36=144KB, VGPR 52 <= 64). 8 j-tiles per block.
__global__ __launch_bounds__(512, 4) void knn_big_kernel(
    const bf16_t* __restrict__ X, const float* __restrict__ sqg, unsigned* __restrict__ pkw)
{
  __shared__ __align__(16) unsigned shm[9216];  // [0,8192): two B-buffers; [8192,8192+NP/JSEG): sq
  const int b = blockIdx.y, i0 = blockIdx.x * 128, seg = blockIdx.z;
  const int jbase = seg * (NP / JSEG);
  const int NT = (NP / JSEG) / 64;              // 8 j-tiles per segment
  const int t = threadIdx.x;
  const bf16_t* __restrict__ Xb = X + (size_t)b * NP * HD;
  const float* __restrict__ sqb = sqg + (size_t)b * NP + jbase;
  for (int u = t; u < NP / JSEG; u += 512) shm[8192 + u] = __float_as_uint(sqb[u]);
  const int lane = t & 63, wv = t >> 6, quad = lane >> 4, l16 = lane & 15;
  const int sw = l16 & 7;
  const bf16_t* Ar = Xb + (size_t)(i0 + wv*16 + l16)*HD + quad*8;
  bf16x8 af0 = *(const bf16x8*)(Ar);
  bf16x8 af1 = *(const bf16x8*)(Ar + 32);
  bf16x8 af2 = *(const bf16x8*)(Ar + 64);
  bf16x8 af3 = *(const bf16x8*)(Ar + 96);
  // staging: 512 threads cover 64 rows x 16 granules, 2 granule-rows each
  const int trow = t >> 4, gcol = t & 15;       // trow in [0,32)
  const int swz = gcol ^ (trow & 7);            // (trow+32)&7 == trow&7
  const bf16_t* gs = Xb + (size_t)(jbase + trow)*HD + gcol*8;
  bf16_t* const bufs = (bf16_t*)shm;
  {
    uint4 g0 = *(const uint4*)(gs);
    uint4 g1 = *(const uint4*)(gs + 32*HD);
    *(uint4*)&bufs[(trow     )*128 + swz*8] = g0;
    *(uint4*)&bufs[(trow + 32)*128 + swz*8] = g1;
  }
  T8_DECL_MAX(Ra); T8_DECL_MAX(Rb); T8_DECL_MAX(Rc); T8_DECL_MAX(Rd);
  __syncthreads();
  const f32x4 z = {0.f, 0.f, 0.f, 0.f};
  const unsigned jrb = 2047u - (unsigned)l16 - (unsigned)jbase;
#define BFR(ct, ks) (*(const bf16x8*)&bufc[(ct*16 + l16)*128 + (((ks*4 + quad) ^ sw) << 3)])
  for (int jt = 0; jt < NT; ++jt) {
    const int j0 = jt * 64;
    const bf16_t* bufc = bufs + (jt & 1) * 8192;
    uint4 g0, g1;
    const bool pf = (jt + 1 < NT);
    if (pf) {
      const bf16_t* gn = gs + (size_t)(jt + 1) * 64 * HD;
      g0 = *(const uint4*)(gn);
      g1 = *(const uint4*)(gn + 32*HD);
    }
    f32x4 ac0 = z, ac1 = z, ac2 = z, ac3 = z;
    ac0 = __builtin_amdgcn_mfma_f32_16x16x32_bf16(af0, BFR(0,0), ac0, 0,0,0);
    ac1 = __builtin_amdgcn_mfma_f32_16x16x32_bf16(af0, BFR(1,0), ac1, 0,0,0);
    ac2 = __builtin_amdgcn_mfma_f32_16x16x32_bf16(af0, BFR(2,0), ac2, 0,0,0);
    ac3 = __builtin_amdgcn_mfma_f32_16x16x32_bf16(af0, BFR(3,0), ac3, 0,0,0);
    ac0 = __builtin_amdgcn_mfma_f32_16x16x32_bf16(af1, BFR(0,1), ac0, 0,0,0);
    ac1 = __builtin_amdgcn_mfma_f32_16x16x32_bf16(af1, BFR(1,1), ac1, 0,0,0);
    ac2 = __builtin_amdgcn_mfma_f32_16x16x32_bf16(af1, BFR(2,1), ac2, 0,0,0);
    ac3 = __builtin_amdgcn_mfma_f32_16x16x32_bf16(af1, BFR(3,1), ac3, 0,0,0);
    ac0 = __builtin_amdgcn_mfma_f32_16x16x32_bf16(af2, BFR(0,2), ac0, 0,0,0);
    ac1 = __builtin_amdgcn_mfma_f32_16x16x32_bf16(af2, BFR(1,2), ac1, 0,0,0);
    ac2 = __builtin_amdgcn_mfma_f32_16x16x32_bf16(af2, BFR(2,2), ac2, 0,0,0);
    ac3 = __builtin_amdgcn_mfma_f32_16x16x32_bf16(af2, BFR(3,2), ac3, 0,0,0);
    ac0 = __builtin_amdgcn_mfma_f32_16x16x32_bf16(af3, BFR(0,3), ac0, 0,0,0);
    ac1 = __builtin_amdgcn_mfma_f32_16x16x32_bf16(af3, BFR(1,3), ac1, 0,0,0);
    ac2 = __builtin_amdgcn_mfma_f32_16x16x32_bf16(af3, BFR(2,3), ac2, 0,0,0);
    ac3 = __builtin_amdgcn_mfma_f32_16x16x32_bf16(af3, BFR(3,3), ac3, 0,0,0);
    const float sq0 = __uint_as_float(shm[8192 + j0      + l16]);
    const float sq1 = __uint_as_float(shm[8192 + j0 + 16 + l16]);
    const float sq2 = __uint_as_float(shm[8192 + j0 + 32 + l16]);
    const float sq3 = __uint_as_float(shm[8192 + j0 + 48 + l16]);
    const unsigned jr0 = jrb - (unsigned)j0;
    const unsigned jr1 = jr0 - 16u, jr2 = jr0 - 32u, jr3 = jr0 - 48u;
    {
      unsigned ka0 = pk_max(__builtin_fmaf(2.f, ac0[0], -sq0), jr0);
      unsigned ka1 = pk_max(__builtin_fmaf(2.f, ac1[0], -sq1), jr1);
      unsigned ka2 = pk_max(__builtin_fmaf(2.f, ac2[0], -sq2), jr2);
      unsigned ka3 = pk_max(__builtin_fmaf(2.f, ac3[0], -sq3), jr3);
      T8_B4_MAX(Ra, ka0, ka1, ka2, ka3);
      unsigned kb0 = pk_max(__builtin_fmaf(2.f, ac0[1], -sq0), jr0);
      unsigned kb1 = pk_max(__builtin_fmaf(2.f, ac1[1], -sq1), jr1);
      unsigned kb2 = pk_max(__builtin_fmaf(2.f, ac2[1], -sq2), jr2);
      unsigned kb3 = pk_max(__builtin_fmaf(2.f, ac3[1], -sq3), jr3);
      T8_B4_MAX(Rb, kb0, kb1, kb2, kb3);
      unsigned kc0 = pk_max(__builtin_fmaf(2.f, ac0[2], -sq0), jr0);
      unsigned kc1 = pk_max(__builtin_fmaf(2.f, ac1[2], -sq1), jr1);
      unsigned kc2 = pk_max(__builtin_fmaf(2.f, ac2[2], -sq2), jr2);
      unsigned kc3 = pk_max(__builtin_fmaf(2.f, ac3[2], -sq3), jr3);
      T8_B4_MAX(Rc, kc0, kc1, kc2, kc3);
      unsigned kd0 = pk_max(__builtin_fmaf(2.f, ac0[3], -sq0), jr0);
      unsigned kd1 = pk_max(__builtin_fmaf(2.f, ac1[3], -sq1), jr1);
      unsigned kd2 = pk_max(__builtin_fmaf(2.f, ac2[3], -sq2), jr2);
      unsigned kd3 = pk_max(__builtin_fmaf(2.f, ac3[3], -sq3), jr3);
      T8_B4_MAX(Rd, kd0, kd1, kd2, kd3);
    }
    if (pf) {
      bf16_t* bufn = bufs + ((jt + 1) & 1) * 8192;
      *(uint4*)&bufn[(trow     )*128 + swz*8] = g0;
      *(uint4*)&bufn[(trow + 32)*128 + swz*8] = g1;
    }
    __syncthreads();
  }
#undef BFR
  // butterfly merge across the 16 j-partitions (lane bits 0-3 = l16); no LDS
  T8_SHMERGE_MAX(Ra, 1) T8_SHMERGE_MAX(Ra, 2) T8_SHMERGE_MAX(Ra, 4) T8_SHMERGE_MAX(Ra, 8)
  T8_SHMERGE_MAX(Rb, 1) T8_SHMERGE_MAX(Rb, 2) T8_SHMERGE_MAX(Rb, 4) T8_SHMERGE_MAX(Rb, 8)
  T8_SHMERGE_MAX(Rc, 1) T8_SHMERGE_MAX(Rc, 2) T8_SHMERGE_MAX(Rc, 4) T8_SHMERGE_MAX(Rc, 8)
  T8_SHMERGE_MAX(Rd, 1) T8_SHMERGE_MAX(Rd, 2) T8_SHMERGE_MAX(Rd, 4) T8_SHMERGE_MAX(Rd, 8)
  if (l16 == 0) {
    const size_t rbase = ((size_t)b*NP + i0 + wv*16 + quad*4);
    unsigned* o = pkw + (rbase*JSEG + seg) * 8;
    o[0]=Ra0; o[1]=Ra1; o[2]=Ra2; o[3]=Ra3; o[4]=Ra4; o[5]=Ra5; o[6]=Ra6; o[7]=Ra7;
    o = pkw + ((rbase+1)*JSEG + seg) * 8;
    o[0]=Rb0; o[1]=Rb1; o[2]=Rb2; o[3]=Rb3; o[4]=Rb4; o[5]=Rb5; o[6]=Rb6; o[7]=Rb7;
    o = pkw + ((rbase+2)*JSEG + seg) * 8;
    o[0]=Rc0; o[1]=Rc1; o[2]=Rc2; o[3]=Rc3; o[4]=Rc4; o[5]=Rc5; o[6]=Rc6; o[7]=Rc7;
    o = pkw + ((rbase+3)*JSEG + seg) * 8;
    o[0]=Rd0; o[1]=Rd1; o[2]=Rd2; o[3]=Rd3; o[4]=Rd4; o[5]=Rd5; o[6]=Rd6; o[7]=Rd7;
  }
}

// ---------------- merge per-segment packed partials -> final indices ----------------
__global__ __launch_bounds__(256) void knn_merge_kernel(const unsigned* __restrict__ pkw,
                                                        int* __restrict__ idxo)
{
  const int row = blockIdx.x * 256 + threadIdx.x;   // < NB*NP
  const unsigned* q = pkw + (size_t)row * JSEG * 8;
  T8_DECL_MAX(F);
#pragma unroll
  for (int m = 0; m < JSEG * 8; ++m) { unsigned v = q[m]; T8_GINS_MAX(F, v); }
  int* o = idxo + (size_t)row * 8;
  o[0] = 2047 - (int)(F0 & 0x7FFu); o[1] = 2047 - (int)(F1 & 0x7FFu);
  o[2] = 2047 - (int)(F2 & 0x7FFu); o[3] = 2047 - (int)(F3 & 0x7FFu);
  o[4] = 2047 - (int)(F4 & 0x7FFu); o[5] = 2047 - (int)(F5 & 0x7FFu);
  o[6] = 2047 - (int)(F6 & 0x7FFu); o[7] = 2047 - (int)(F7 & 0x7FFu);
}

// ---------------- edge MLP: barrier-free, all-register h1 fragments ----------------
__global__ __launch_bounds__(256, 2) void edge_mlp_kernel(
    const bf16_t* __restrict__ P, const bf16_t* __restrict__ Q, const int* __restrict__ idx,
    const bf16_t* __restrict__ W2T, const float* __restrict__ b2,
    bf16_t* __restrict__ xout, float* __restrict__ pooled, int poolOff)
{
  const int b = blockIdx.y;
  const size_t bNP = (size_t)b * NP;
  const int t = threadIdx.x;
  const int lane = t & 63, w = t >> 6, quad = lane >> 4, l16 = lane & 15;
  const int pbase = blockIdx.x * 64 + w * 16;
  const bf16_t* __restrict__ Wb = W2T + (size_t)l16 * HD + quad * 8;
#define LDB(ks, ct) const bf16x8 B##ks##ct = *(const bf16x8*)&Wb[ct*16*HD + ks*32];
  LDB(0,0) LDB(0,1) LDB(0,2) LDB(0,3) LDB(0,4) LDB(0,5) LDB(0,6) LDB(0,7)
  LDB(1,0) LDB(1,1) LDB(1,2) LDB(1,3) LDB(1,4) LDB(1,5) LDB(1,6) LDB(1,7)
#undef LDB
  const float bv0 = b2[  0 + l16], bv1 = b2[ 16 + l16], bv2 = b2[ 32 + l16], bv3 = b2[ 48 + l16];
  const float bv4 = b2[ 64 + l16], bv5 = b2[ 80 + l16], bv6 = b2[ 96 + l16], bv7 = b2[112 + l16];
  float pa0=0.f, pa1=0.f, pa2=0.f, pa3=0.f, pa4=0.f, pa5=0.f, pa6=0.f, pa7=0.f;
  const f32x4 z = {0.f, 0.f, 0.f, 0.f};
  for (int it = 0; it < 8; ++it) {
    const int ip = pbase + it*2 + (l16 >> 3);
    const int j = idx[(bNP + ip)*8 + (l16 & 7)];
    const bf16_t* Qr = Q + (bNP + (unsigned)j)*HD + quad*8;
    const bf16_t* Pr = P + (bNP + ip)*HD + quad*8;
    bf16x8 q0 = *(const bf16x8*)(Qr     );
    bf16x8 q1 = *(const bf16x8*)(Qr + 32);
    bf16x8 q2 = *(const bf16x8*)(Qr + 64);
    bf16x8 q3 = *(const bf16x8*)(Qr + 96);
    bf16x8 p0 = *(const bf16x8*)(Pr     );
    bf16x8 p1 = *(const bf16x8*)(Pr + 32);
    bf16x8 p2 = *(const bf16x8*)(Pr + 64);
    bf16x8 p3 = *(const bf16x8*)(Pr + 96);
    bf16x8 af0, af1, af2, af3;
#pragma unroll
    for (int k = 0; k < 8; ++k) {
      af0[k] = (bf16_t)fmaxf((float)p0[k] + (float)q0[k], 0.f);
      af1[k] = (bf16_t)fmaxf((float)p1[k] + (float)q1[k], 0.f);
      af2[k] = (bf16_t)fmaxf((float)p2[k] + (float)q2[k], 0.f);
      af3[k] = (bf16_t)fmaxf((float)p3[k] + (float)q3[k], 0.f);
    }
    f32x4 ac0=z, ac1=z, ac2=z, ac3=z, ac4=z, ac5=z, ac6=z, ac7=z;
    ac0 = __builtin_amdgcn_mfma_f32_16x16x32_bf16(af0, B00, ac0, 0,0,0);
    ac1 = __builtin_amdgcn_mfma_f32_16x16x32_bf16(af0, B01, ac1, 0,0,0);
    ac2 = __builtin_amdgcn_mfma_f32_16x16x32_bf16(af0, B02, ac2, 0,0,0);
    ac3 = __builtin_amdgcn_mfma_f32_16x16x32_bf16(af0, B03, ac3, 0,0,0);
    ac4 = __builtin_amdgcn_mfma_f32_16x16x32_bf16(af0, B04, ac4, 0,0,0);
    ac5 = __builtin_amdgcn_mfma_f32_16x16x32_bf16(af0, B05, ac5, 0,0,0);
    ac6 = __builtin_amdgcn_mfma_f32_16x16x32_bf16(af0, B06, ac6, 0,0,0);
    ac7 = __builtin_amdgcn_mfma_f32_16x16x32_bf16(af0, B07, ac7, 0,0,0);
    ac0 = __builtin_amdgcn_mfma_f32_16x16x32_bf16(af1, B10, ac0, 0,0,0);
    ac1 = __builtin_amdgcn_mfma_f32_16x16x32_bf16(af1, B11, ac1, 0,0,0);
    ac2 = __builtin_amdgcn_mfma_f32_16x16x32_bf16(af1, B12, ac2, 0,0,0);
    ac3 = __builtin_amdgcn_mfma_f32_16x16x32_bf16(af1, B13, ac3, 0,0,0);
    ac4 = __builtin_amdgcn_mfma_f32_16x16x32_bf16(af1, B14, ac4, 0,0,0);
    ac5 = __builtin_amdgcn_mfma_f32_16x16x32_bf16(af1, B15, ac5, 0,0,0);
    ac6 = __builtin_amdgcn_mfma_f32_16x16x32_bf16(af1, B16, ac6, 0,0,0);
    ac7 = __builtin_amdgcn_mfma_f32_16x16x32_bf16(af1, B17, ac7, 0,0,0);
#define MM2(ct, accv) { \
    bf16x8 b2f = *(const bf16x8*)&Wb[ct*16*HD + 2*32]; \
    accv = __builtin_amdgcn_mfma_f32_16x16x32_bf16(af2, b2f, accv, 0,0,0); \
    bf16x8 b3f = *(const bf16x8*)&Wb[ct*16*HD + 3*32]; \
    accv = __builtin_amdgcn_mfma_f32_16x16x32_bf16(af3, b3f, accv, 0,0,0); }
    MM2(0, ac0) MM2(1, ac1) MM2(2, ac2) MM2(3, ac3)
    MM2(4, ac4) MM2(5, ac5) MM2(6, ac6) MM2(7, ac7)
#undef MM2
    const int ipt = pbase + it*2 + (quad >> 1);
    bf16_t* xr = xout + (bNP + ipt)*HD + l16;
#define EPI(ct, accv, bvv, pav) { \
    float s = fmaxf(accv[0]+bvv,0.f) + fmaxf(accv[1]+bvv,0.f) \
            + fmaxf(accv[2]+bvv,0.f) + fmaxf(accv[3]+bvv,0.f); \
    s += __shfl_xor(s, 16); \
    if ((quad & 1) == 0) xr[ct*16] = (bf16_t)(s * 0.125f); \
    pav += s + __shfl_xor(s, 32); }
    EPI(0, ac0, bv0, pa0) EPI(1, ac1, bv1, pa1) EPI(2, ac2, bv2, pa2) EPI(3, ac3, bv3, pa3)
    EPI(4, ac4, bv4, pa4) EPI(5, ac5, bv5, pa5) EPI(6, ac6, bv6, pa6) EPI(7, ac7, bv7, pa7)
#undef EPI
  }
  if (quad == 0) {
    float* pr = pooled + b*384 + poolOff + l16;
    atomicAdd(pr +   0, pa0 * 0.125f);
    atomicAdd(pr +  16, pa1 * 0.125f);
    atomicAdd(pr +  32, pa2 * 0.125f);
    atomicAdd(pr +  48, pa3 * 0.125f);
    atomicAdd(pr +  64, pa4 * 0.125f);
    atomicAdd(pr +  80, pa5 * 0.125f);
    atomicAdd(pr +  96, pa6 * 0.125f);
    atomicAdd(pr + 112, pa7 * 0.125f);
  }
}

// ---------------- final pooled MLP ----------------
__global__ __launch_bounds__(128) void final_mlp_kernel(
    const float* __restrict__ pooled, const float* __restrict__ W1, const float* __restrict__ b1v,
    const float* __restrict__ W2, const float* __restrict__ b2v, float* __restrict__ out)
{
  __shared__ float hb[128];
  int b = blockIdx.x, g = threadIdx.x;
  float h = b1v[g];
  const float inv = 1.0f / (float)NP;
  for (int c = 0; c < 384; ++c) h += pooled[b*384 + c] * inv * W1[c*128 + g];
  hb[g] = fmaxf(h, 0.f);
  __syncthreads();
  if (g < 2) {
    float o = b2v[g];
    for (int k2 = 0; k2 < 128; ++k2) o += hb[k2] * W2[k2*2 + g];
    out[b*2 + g] = o;
  }
}

extern "C" void kernel_launch(void* const* d_in, const int* in_sizes, int n_in,
                              void* d_out, int out_size, void* d_ws, size_t ws_size,
                              hipStream_t stream) {
  (void)in_sizes; (void)n_in; (void)out_size; (void)ws_size;
  const float* x    = (const float*)d_in[0];
  const float* c1W1 = (const float*)d_in[1];
  const float* c1b1 = (const float*)d_in[2];
  const float* c1W2 = (const float*)d_in[3];
  const float* c1b2 = (const float*)d_in[4];
  const float* c2W1 = (const float*)d_in[5];
  const float* c2b1 = (const float*)d_in[6];
  const float* c2W2 = (const float*)d_in[7];
  const float* c2b2 = (const float*)d_in[8];
  const float* c3W1 = (const float*)d_in[9];
  const float* c3b1 = (const float*)d_in[10];
  const float* c3W2 = (const float*)d_in[11];
  const float* c3b2 = (const float*)d_in[12];
  const float* mW1  = (const float*)d_in[13];
  const float* mb1  = (const float*)d_in[14];
  const float* mW2  = (const float*)d_in[15];
  const float* mb2  = (const float*)d_in[16];

  char* wsp = (char*)d_ws;
  auto carve = [&](size_t bytes) -> void* {
    void* p = (void*)wsp; wsp += (bytes + 255) & ~(size_t)255; return p;
  };
  bf16_t* x1b  = (bf16_t*)carve((size_t)NB*NP*HD*2);
  bf16_t* x2b  = (bf16_t*)carve((size_t)NB*NP*HD*2);
  bf16_t* x3b  = (bf16_t*)carve((size_t)NB*NP*HD*2);
  bf16_t* Pbuf = (bf16_t*)carve((size_t)NB*NP*HD*2);
  bf16_t* Qbuf = (bf16_t*)carve((size_t)NB*NP*HD*2);
  float*  sqb  = (float*)carve((size_t)NB*NP*4);
  int*    idxb = (int*)carve((size_t)NB*NP*8*4);
  unsigned* pkw = (unsigned*)carve((size_t)NB*NP*JSEG*8*4);
  bf16_t* W2T1 = (bf16_t*)carve(128*128*2);
  bf16_t* WpT2 = (bf16_t*)carve(128*128*2);
  bf16_t* WqT2 = (bf16_t*)carve(128*128*2);
  bf16_t* W2T2 = (bf16_t*)carve(128*128*2);
  bf16_t* WpT3 = (bf16_t*)carve(128*128*2);
  bf16_t* WqT3 = (bf16_t*)carve(128*128*2);
  bf16_t* W2T3 = (bf16_t*)carve(128*128*2);
  float*  pooled = (float*)carve((size_t)NB*384*4);

  hipMemsetAsync(pooled, 0, (size_t)NB*384*4, stream);
  wprep_kernel<<<448, 256, 0, stream>>>(c1W2, c2W1, c2W2, c3W1, c3W2,
                                        W2T1, WpT2, WqT2, W2T2, WpT3, WqT3, W2T3);
  // layer 1
  pq1_kernel<<<4096, 256, 0, stream>>>(x, c1W1, c1b1, Pbuf, Qbuf);
  knn1_kernel<<<dim3(NP/32, NB), 256, 0, stream>>>(x, idxb);
  edge_mlp_kernel<<<dim3(NP/64, NB), 256, 0, stream>>>(Pbuf, Qbuf, idxb, W2T1, c1b2, x1b, pooled, 0);
  // layer 2
  prep_sq_kernel<<<128, 256, 0, stream>>>(x1b, sqb);
  pq_gemm_kernel<<<dim3(NB*NP/128, 2), 256, 0, stream>>>(x1b, WpT2, WqT2, c2b1, Pbuf, Qbuf);
  knn_big_kernel<<<dim3(NP/128, NB, JSEG), 512, 0, stream>>>(x1b, sqb, pkw);
  knn_merge_kernel<<<NB*NP/256, 256, 0, stream>>>(pkw, idxb);
  edge_mlp_kernel<<<dim3(NP/64, NB), 256, 0, stream>>>(Pbuf, Qbuf, idxb, W2T2, c2b2, x2b, pooled, 128);
  // layer 3
  prep_sq_kernel<<<128, 256, 0, stream>>>(x2b, sqb);
  pq_gemm_kernel<<<dim3(NB*NP/128, 2), 256, 0, stream>>>(x2b, WpT3, WqT3, c3b1, Pbuf, Qbuf);
  knn_big_kernel<<<dim3(NP/128, NB, JSEG), 512, 0, stream>>>(x2b, sqb, pkw);
  knn_merge_kernel<<<NB*NP/256, 256, 0, stream>>>(pkw, idxb);
  edge_mlp_kernel<<<dim3(NP/64, NB), 256, 0, stream>>>(Pbuf, Qbuf, idxb, W2T3, c3b2, x3b, pooled, 256);
  // head
  final_mlp_kernel<<<NB, 128, 0, stream>>>(pooled, mW1, mb1, mW2, mb2, (float*)d_out);
}

// Round 14
// 367.492 us; speedup vs baseline: 1.0474x; 1.0474x over previous
//
#include <hip/hip_runtime.h>

#define NB 16
#define NP 2048
#define HD 128
#define LDP 136   // padded LDS row (bf16 elems)
#define JSEG 2    // j-range split for knn_big (2 is measured optimum; 4 regressed: fixed
                  // per-block costs dominate, occupancy is scheduler-capped at ~11 waves/CU)

typedef __bf16 bf16_t;
typedef bf16_t bf16x8 __attribute__((ext_vector_type(8)));
typedef bf16_t bf16x4 __attribute__((ext_vector_type(4)));
typedef float  f32x4  __attribute__((ext_vector_type(4)));

// ---------------- packed-key top-8 machinery ----------------
__device__ __forceinline__ unsigned pk_max(float k, unsigned jrev) {
  unsigned u = __float_as_uint(k);
  unsigned s = u ^ (unsigned)(((int)u >> 31) | 0x80000000);
  return (s & 0xFFFFF800u) | jrev;
}
__device__ __forceinline__ unsigned pk_min(float k, unsigned j) {
  unsigned u = __float_as_uint(k);
  unsigned s = u ^ (unsigned)(((int)u >> 31) | 0x80000000);
  return (s & 0xFFFFF800u) | j;
}

#define T8_DECL_MAX(p) unsigned p##0=0u,p##1=0u,p##2=0u,p##3=0u,p##4=0u,p##5=0u,p##6=0u,p##7=0u
#define T8_STEP_MAX(b,cc) { unsigned t_ = ((b)<(cc)?(b):(cc)); (b) = ((b)>(cc)?(b):(cc)); (cc) = t_; }
#define T8_INS_MAX(p,c) { unsigned cc_=(c); \
  T8_STEP_MAX(p##0,cc_) T8_STEP_MAX(p##1,cc_) T8_STEP_MAX(p##2,cc_) T8_STEP_MAX(p##3,cc_) \
  T8_STEP_MAX(p##4,cc_) T8_STEP_MAX(p##5,cc_) T8_STEP_MAX(p##6,cc_) T8_STEP_MAX(p##7,cc_) }
#define T8_GINS_MAX(p,c) { unsigned cg_=(c); if (cg_ > p##7) { T8_INS_MAX(p, cg_) } }

#define T8_DECL_MIN(p) unsigned p##0=0xFFFFFFFFu,p##1=0xFFFFFFFFu,p##2=0xFFFFFFFFu,p##3=0xFFFFFFFFu,p##4=0xFFFFFFFFu,p##5=0xFFFFFFFFu,p##6=0xFFFFFFFFu,p##7=0xFFFFFFFFu
#define T8_STEP_MIN(b,cc) { unsigned t_ = ((b)>(cc)?(b):(cc)); (b) = ((b)<(cc)?(b):(cc)); (cc) = t_; }
#define T8_INS_MIN(p,c) { unsigned cc_=(c); \
  T8_STEP_MIN(p##0,cc_) T8_STEP_MIN(p##1,cc_) T8_STEP_MIN(p##2,cc_) T8_STEP_MIN(p##3,cc_) \
  T8_STEP_MIN(p##4,cc_) T8_STEP_MIN(p##5,cc_) T8_STEP_MIN(p##6,cc_) T8_STEP_MIN(p##7,cc_) }
#define T8_GINS_MIN(p,c) { unsigned cg_=(c); if (cg_ < p##7) { T8_INS_MIN(p, cg_) } }

// ---- batched bitonic top-8 update (exact, branchless; faiss-style) ----
#define CMPX_DESC(a,b) { unsigned h_=((a)>(b)?(a):(b)); unsigned l_=((a)<(b)?(a):(b)); (a)=h_; (b)=l_; }
#define CMPX_ASC(a,b)  { unsigned l_=((a)<(b)?(a):(b)); unsigned h_=((a)>(b)?(a):(b)); (a)=l_; (b)=h_; }

#define T8_B4_MAX(p, d0,d1,d2,d3) { \
  unsigned x0_=(d0), x1_=(d1), x2_=(d2), x3_=(d3); \
  CMPX_DESC(x0_,x1_) CMPX_DESC(x2_,x3_) CMPX_DESC(x0_,x2_) CMPX_DESC(x1_,x3_) CMPX_DESC(x1_,x2_) \
  p##4 = p##4 > x3_ ? p##4 : x3_; \
  p##5 = p##5 > x2_ ? p##5 : x2_; \
  p##6 = p##6 > x1_ ? p##6 : x1_; \
  p##7 = p##7 > x0_ ? p##7 : x0_; \
  CMPX_DESC(p##0,p##4) CMPX_DESC(p##1,p##5) CMPX_DESC(p##2,p##6) CMPX_DESC(p##3,p##7) \
  CMPX_DESC(p##0,p##2) CMPX_DESC(p##1,p##3) CMPX_DESC(p##4,p##6) CMPX_DESC(p##5,p##7) \
  CMPX_DESC(p##0,p##1) CMPX_DESC(p##2,p##3) CMPX_DESC(p##4,p##5) CMPX_DESC(p##6,p##7) }

#define T8_B4_MIN(p, d0,d1,d2,d3) { \
  unsigned x0_=(d0), x1_=(d1), x2_=(d2), x3_=(d3); \
  CMPX_ASC(x0_,x1_) CMPX_ASC(x2_,x3_) CMPX_ASC(x0_,x2_) CMPX_ASC(x1_,x3_) CMPX_ASC(x1_,x2_) \
  p##4 = p##4 < x3_ ? p##4 : x3_; \
  p##5 = p##5 < x2_ ? p##5 : x2_; \
  p##6 = p##6 < x1_ ? p##6 : x1_; \
  p##7 = p##7 < x0_ ? p##7 : x0_; \
  CMPX_ASC(p##0,p##4) CMPX_ASC(p##1,p##5) CMPX_ASC(p##2,p##6) CMPX_ASC(p##3,p##7) \
  CMPX_ASC(p##0,p##2) CMPX_ASC(p##1,p##3) CMPX_ASC(p##4,p##6) CMPX_ASC(p##5,p##7) \
  CMPX_ASC(p##0,p##1) CMPX_ASC(p##2,p##3) CMPX_ASC(p##4,p##5) CMPX_ASC(p##6,p##7) }

// ---- shuffle butterfly merge: merge own sorted-8(desc) with lane^mask partner's ----
#define T8_SHMERGE_MAX(p, mask) { \
  unsigned o_; \
  o_ = (unsigned)__shfl_xor((int)p##7, mask); p##0 = p##0 > o_ ? p##0 : o_; \
  o_ = (unsigned)__shfl_xor((int)p##6, mask); p##1 = p##1 > o_ ? p##1 : o_; \
  o_ = (unsigned)__shfl_xor((int)p##5, mask); p##2 = p##2 > o_ ? p##2 : o_; \
  o_ = (unsigned)__shfl_xor((int)p##4, mask); p##3 = p##3 > o_ ? p##3 : o_; \
  o_ = (unsigned)__shfl_xor((int)p##3, mask); p##4 = p##4 > o_ ? p##4 : o_; \
  o_ = (unsigned)__shfl_xor((int)p##2, mask); p##5 = p##5 > o_ ? p##5 : o_; \
  o_ = (unsigned)__shfl_xor((int)p##1, mask); p##6 = p##6 > o_ ? p##6 : o_; \
  o_ = (unsigned)__shfl_xor((int)p##0, mask); p##7 = p##7 > o_ ? p##7 : o_; \
  CMPX_DESC(p##0,p##4) CMPX_DESC(p##1,p##5) CMPX_DESC(p##2,p##6) CMPX_DESC(p##3,p##7) \
  CMPX_DESC(p##0,p##2) CMPX_DESC(p##1,p##3) CMPX_DESC(p##4,p##6) CMPX_DESC(p##5,p##7) \
  CMPX_DESC(p##0,p##1) CMPX_DESC(p##2,p##3) CMPX_DESC(p##4,p##5) CMPX_DESC(p##6,p##7) }

// ---------------- weight prep ----------------
__global__ __launch_bounds__(256) void wprep_kernel(
    const float* __restrict__ c1W2, const float* __restrict__ c2W1, const float* __restrict__ c2W2,
    const float* __restrict__ c3W1, const float* __restrict__ c3W2,
    bf16_t* __restrict__ W2T1, bf16_t* __restrict__ WpT2, bf16_t* __restrict__ WqT2,
    bf16_t* __restrict__ W2T2, bf16_t* __restrict__ WpT3, bf16_t* __restrict__ WqT3,
    bf16_t* __restrict__ W2T3)
{
  int tid = blockIdx.x * 256 + threadIdx.x;     // < 7*16384
  int m = tid >> 14, e = tid & 16383;
  int r = e >> 7, c = e & 127;
  switch (m) {
    case 0: W2T1[r*128+c] = (bf16_t)c1W2[c*128+r]; break;
    case 1: WpT2[r*128+c] = (bf16_t)(c2W1[c*128+r] - c2W1[(128+c)*128+r]); break;
    case 2: WqT2[r*128+c] = (bf16_t)c2W1[(128+c)*128+r]; break;
    case 3: W2T2[r*128+c] = (bf16_t)c2W2[c*128+r]; break;
    case 4: WpT3[r*128+c] = (bf16_t)(c3W1[c*128+r] - c3W1[(128+c)*128+r]); break;
    case 5: WqT3[r*128+c] = (bf16_t)c3W1[(128+c)*128+r]; break;
    case 6: W2T3[r*128+c] = (bf16_t)c3W2[c*128+r]; break;
  }
}

// ---------------- layer-1 P/Q (bf16 out) ----------------
__global__ __launch_bounds__(256) void pq1_kernel(
    const float* __restrict__ x, const float* __restrict__ W1, const float* __restrict__ b1,
    bf16_t* __restrict__ P, bf16_t* __restrict__ Q)
{
  int tid = blockIdx.x * 256 + threadIdx.x;     // < 32768*32
  int row = tid >> 5, c0 = (tid & 31) * 4;
  float x0 = x[row*3+0], x1 = x[row*3+1], x2 = x[row*3+2];
  bf16x4 pv, qv;
#pragma unroll
  for (int u = 0; u < 4; ++u) {
    int c = c0 + u;
    float wq0 = W1[3*128+c], wq1 = W1[4*128+c], wq2 = W1[5*128+c];
    float wp0 = W1[0*128+c]-wq0, wp1 = W1[1*128+c]-wq1, wp2 = W1[2*128+c]-wq2;
    pv[u] = (bf16_t)(x0*wp0 + x1*wp1 + x2*wp2 + b1[c]);
    qv[u] = (bf16_t)(x0*wq0 + x1*wq1 + x2*wq2);
  }
  *(bf16x4*)&P[(size_t)row*HD + c0] = pv;
  *(bf16x4*)&Q[(size_t)row*HD + c0] = qv;
}

// ---------------- kNN layer 1 (32 rows/block, 8 partitions, batched bitonic top-8) ----------------
__global__ __launch_bounds__(256) void knn1_kernel(const float* __restrict__ x, int* __restrict__ idxo)
{
  __shared__ __align__(16) float4 pts[NP];      // 32 KB: (x, y, z, |x|^2)
  __shared__ unsigned mrg[32 * 64];             // 8 KB merge scratch (packed keys)
  const int b = blockIdx.y, i0 = blockIdx.x * 32;
  const int t = threadIdx.x;
  const float* __restrict__ xb = x + (size_t)b * NP * 3;
  for (int u = t; u < NP; u += 256) {
    float a0 = xb[u*3+0], a1 = xb[u*3+1], a2 = xb[u*3+2];
    pts[u] = make_float4(a0, a1, a2, a0*a0 + a1*a1 + a2*a2);
  }
  __syncthreads();
  const int selr = t >> 3, selp = t & 7;        // 32 rows x 8 partitions
  const float4 pi = pts[i0 + selr];
  T8_DECL_MIN(L);
#pragma unroll 2
  for (int jj = 0; jj < NP / 32; ++jj) {
    const int jb = jj * 32 + selp;
    float4 p0 = pts[jb];
    float4 p1 = pts[jb + 8];
    float4 p2 = pts[jb + 16];
    float4 p3 = pts[jb + 24];
    float k0 = p0.w - 2.0f * (p0.x*pi.x + p0.y*pi.y + p0.z*pi.z);
    float k1 = p1.w - 2.0f * (p1.x*pi.x + p1.y*pi.y + p1.z*pi.z);
    float k2 = p2.w - 2.0f * (p2.x*pi.x + p2.y*pi.y + p2.z*pi.z);
    float k3 = p3.w - 2.0f * (p3.x*pi.x + p3.y*pi.y + p3.z*pi.z);
    T8_B4_MIN(L, pk_min(k0, (unsigned)jb), pk_min(k1, (unsigned)(jb+8)),
                 pk_min(k2, (unsigned)(jb+16)), pk_min(k3, (unsigned)(jb+24)));
  }
  {
    unsigned* e = &mrg[selr*64 + selp*8];
    e[0]=L0; e[1]=L1; e[2]=L2; e[3]=L3; e[4]=L4; e[5]=L5; e[6]=L6; e[7]=L7;
  }
  __syncthreads();
  if (t < 32) {
    T8_DECL_MIN(F);
    const unsigned* q = &mrg[t*64];
#pragma unroll
    for (int m = 0; m < 64; ++m) { unsigned v = q[m]; T8_GINS_MIN(F, v); }
    int* o = idxo + ((size_t)b*NP + i0 + t) * 8;
    o[0] = (int)(F0 & 0x7FFu); o[1] = (int)(F1 & 0x7FFu);
    o[2] = (int)(F2 & 0x7FFu); o[3] = (int)(F3 & 0x7FFu);
    o[4] = (int)(F4 & 0x7FFu); o[5] = (int)(F5 & 0x7FFu);
    o[6] = (int)(F6 & 0x7FFu); o[7] = (int)(F7 & 0x7FFu);
  }
}

// ---------------- bf16 row norms ----------------
__global__ __launch_bounds__(256) void prep_sq_kernel(const bf16_t* __restrict__ X, float* __restrict__ sqg)
{
  int r = blockIdx.x * 256 + threadIdx.x;       // < 32768
  const bf16_t* row = X + (size_t)r * HD;
  float s = 0.f;
#pragma unroll
  for (int c = 0; c < HD; c += 8) {
    bf16x8 v = *(const bf16x8*)&row[c];
#pragma unroll
    for (int q = 0; q < 8; ++q) { float f = (float)v[q]; s += f * f; }
  }
  sqg[r] = s;
}

// ---------------- P/Q GEMM for layers 2/3 (bf16 out) ----------------
__global__ __launch_bounds__(256) void pq_gemm_kernel(
    const bf16_t* __restrict__ X, const bf16_t* __restrict__ WpT, const bf16_t* __restrict__ WqT,
    const float* __restrict__ b1, bf16_t* __restrict__ P, bf16_t* __restrict__ Q)
{
  __shared__ __align__(16) bf16_t At[128 * LDP];
  const int r0 = blockIdx.x * 128;
  const bool isP = (blockIdx.y == 0);
  const bf16_t* __restrict__ WT = isP ? WpT : WqT;
  bf16_t* __restrict__ Out = isP ? P : Q;
  const int t = threadIdx.x;
  for (int u = t; u < 2048; u += 256) {
    int r = u >> 4, c = (u & 15) * 8;
    *(bf16x8*)&At[r*LDP + c] = *(const bf16x8*)&X[(size_t)(r0 + r)*HD + c];
  }
  __syncthreads();
  const int lane = t & 63, w = t >> 6, quad = lane >> 4, l16 = lane & 15;
  f32x4 acc[2][8];
  f32x4 z = {0.f, 0.f, 0.f, 0.f};
#pragma unroll
  for (int rt = 0; rt < 2; ++rt)
#pragma unroll
    for (int ct = 0; ct < 8; ++ct) acc[rt][ct] = z;
#pragma unroll
  for (int ks = 0; ks < 4; ++ks) {
    const int kk = ks*32 + quad*8;
    bf16x8 a0 = *(const bf16x8*)&At[(w*32 + l16)*LDP + kk];
    bf16x8 a1 = *(const bf16x8*)&At[(w*32 + 16 + l16)*LDP + kk];
#pragma unroll
    for (int ct = 0; ct < 8; ++ct) {
      bf16x8 bb = *(const bf16x8*)&WT[(ct*16 + l16)*HD + kk];
      acc[0][ct] = __builtin_amdgcn_mfma_f32_16x16x32_bf16(a0, bb, acc[0][ct], 0, 0, 0);
      acc[1][ct] = __builtin_amdgcn_mfma_f32_16x16x32_bf16(a1, bb, acc[1][ct], 0, 0, 0);
    }
  }
#pragma unroll
  for (int rt = 0; rt < 2; ++rt)
#pragma unroll
    for (int ct = 0; ct < 8; ++ct) {
      float bv = isP ? b1[ct*16 + l16] : 0.f;
#pragma unroll
      for (int r = 0; r < 4; ++r) {
        int row = w*32 + rt*16 + quad*4 + r;
        Out[(size_t)(r0 + row)*HD + ct*16 + l16] = (bf16_t)(acc[rt][ct][r] + bv);
      }
    }
}

// ---------------- fused Gram(MFMA) + bitonic top-8; 8 waves share B-tile; shfl merge ----------------
// 512 threads = 8 waves x 16 rows = 128 i-rows/block. __launch_bounds__(512, 4):
// 4 waves/EU -> 128-VGPR budget (VGPR=52 measured, no spill). JSEG=2 -> 512 blocks.
__global__ __launch_bounds__(512, 4) void knn_big_kernel(
    const bf16_t* __restrict__ X, const float* __restrict__ sqg, unsigned* __restrict__ pkw)
{
  __shared__ __align__(16) unsigned shm[9216];  // [0,8192): two B-buffers; [8192,9216): sq
  const int b = blockIdx.y, i0 = blockIdx.x * 128, seg = blockIdx.z;
  const int jbase = seg * (NP / JSEG);
  const int NT = (NP / JSEG) / 64;              // 16 j-tiles per segment
  const int t = threadIdx.x;
  const bf16_t* __restrict__ Xb = X + (size_t)b * NP * HD;
  const float* __restrict__ sqb = sqg + (size_t)b * NP + jbase;
  for (int u = t; u < NP / JSEG; u += 512) shm[8192 + u] = __float_as_uint(sqb[u]);
  const int lane = t & 63, wv = t >> 6, quad = lane >> 4, l16 = lane & 15;
  const int sw = l16 & 7;
  const bf16_t* Ar = Xb + (size_t)(i0 + wv*16 + l16)*HD + quad*8;
  bf16x8 af0 = *(const bf16x8*)(Ar);
  bf16x8 af1 = *(const bf16x8*)(Ar + 32);
  bf16x8 af2 = *(const bf16x8*)(Ar + 64);
  bf16x8 af3 = *(const bf16x8*)(Ar + 96);
  // staging: 512 threads cover 64 rows x 16 granules, 2 granule-rows each
  const int trow = t >> 4, gcol = t & 15;       // trow in [0,32)
  const int swz = gcol ^ (trow & 7);            // (trow+32)&7 == trow&7
  const bf16_t* gs = Xb + (size_t)(jbase + trow)*HD + gcol*8;
  bf16_t* const bufs = (bf16_t*)shm;
  {
    uint4 g0 = *(const uint4*)(gs);
    uint4 g1 = *(const uint4*)(gs + 32*HD);
    *(uint4*)&bufs[(trow     )*128 + swz*8] = g0;
    *(uint4*)&bufs[(trow + 32)*128 + swz*8] = g1;
  }
  T8_DECL_MAX(Ra); T8_DECL_MAX(Rb); T8_DECL_MAX(Rc); T8_DECL_MAX(Rd);
  __syncthreads();
  const f32x4 z = {0.f, 0.f, 0.f, 0.f};
  const unsigned jrb = 2047u - (unsigned)l16 - (unsigned)jbase;
#define BFR(ct, ks) (*(const bf16x8*)&bufc[(ct*16 + l16)*128 + (((ks*4 + quad) ^ sw) << 3)])
  for (int jt = 0; jt < NT; ++jt) {
    const int j0 = jt * 64;
    const bf16_t* bufc = bufs + (jt & 1) * 8192;
    uint4 g0, g1;
    const bool pf = (jt + 1 < NT);
    if (pf) {
      const bf16_t* gn = gs + (size_t)(jt + 1) * 64 * HD;
      g0 = *(const uint4*)(gn);
      g1 = *(const uint4*)(gn + 32*HD);
    }
    f32x4 ac0 = z, ac1 = z, ac2 = z, ac3 = z;
    ac0 = __builtin_amdgcn_mfma_f32_16x16x32_bf16(af0, BFR(0,0), ac0, 0,0,0);
    ac1 = __builtin_amdgcn_mfma_f32_16x16x32_bf16(af0, BFR(1,0), ac1, 0,0,0);
    ac2 = __builtin_amdgcn_mfma_f32_16x16x32_bf16(af0, BFR(2,0), ac2, 0,0,0);
    ac3 = __builtin_amdgcn_mfma_f32_16x16x32_bf16(af0, BFR(3,0), ac3, 0,0,0);
    ac0 = __builtin_amdgcn_mfma_f32_16x16x32_bf16(af1, BFR(0,1), ac0, 0,0,0);
    ac1 = __builtin_amdgcn_mfma_f32_16x16x32_bf16(af1, BFR(1,1), ac1, 0,0,0);
    ac2 = __builtin_amdgcn_mfma_f32_16x16x32_bf16(af1, BFR(2,1), ac2, 0,0,0);
    ac3 = __builtin_amdgcn_mfma_f32_16x16x32_bf16(af1, BFR(3,1), ac3, 0,0,0);
    ac0 = __builtin_amdgcn_mfma_f32_16x16x32_bf16(af2, BFR(0,2), ac0, 0,0,0);
    ac1 = __builtin_amdgcn_mfma_f32_16x16x32_bf16(af2, BFR(1,2), ac1, 0,0,0);
    ac2 = __builtin_amdgcn_mfma_f32_16x16x32_bf16(af2, BFR(2,2), ac2, 0,0,0);
    ac3 = __builtin_amdgcn_mfma_f32_16x16x32_bf16(af2, BFR(3,2), ac3, 0,0,0);
    ac0 = __builtin_amdgcn_mfma_f32_16x16x32_bf16(af3, BFR(0,3), ac0, 0,0,0);
    ac1 = __builtin_amdgcn_mfma_f32_16x16x32_bf16(af3, BFR(1,3), ac1, 0,0,0);
    ac2 = __builtin_amdgcn_mfma_f32_16x16x32_bf16(af3, BFR(2,3), ac2, 0,0,0);
    ac3 = __builtin_amdgcn_mfma_f32_16x16x32_bf16(af3, BFR(3,3), ac3, 0,0,0);
    const float sq0 = __uint_as_float(shm[8192 + j0      + l16]);
    const float sq1 = __uint_as_float(shm[8192 + j0 + 16 + l16]);
    const float sq2 = __uint_as_float(shm[8192 + j0 + 32 + l16]);
    const float sq3 = __uint_as_float(shm[8192 + j0 + 48 + l16]);
    const unsigned jr0 = jrb - (unsigned)j0;
    const unsigned jr1 = jr0 - 16u, jr2 = jr0 - 32u, jr3 = jr0 - 48u;
    {
      unsigned ka0 = pk_max(__builtin_fmaf(2.f, ac0[0], -sq0), jr0);
      unsigned ka1 = pk_max(__builtin_fmaf(2.f, ac1[0], -sq1), jr1);
      unsigned ka2 = pk_max(__builtin_fmaf(2.f, ac2[0], -sq2), jr2);
      unsigned ka3 = pk_max(__builtin_fmaf(2.f, ac3[0], -sq3), jr3);
      T8_B4_MAX(Ra, ka0, ka1, ka2, ka3);
      unsigned kb0 = pk_max(__builtin_fmaf(2.f, ac0[1], -sq0), jr0);
      unsigned kb1 = pk_max(__builtin_fmaf(2.f, ac1[1], -sq1), jr1);
      unsigned kb2 = pk_max(__builtin_fmaf(2.f, ac2[1], -sq2), jr2);
      unsigned kb3 = pk_max(__builtin_fmaf(2.f, ac3[1], -sq3), jr3);
      T8_B4_MAX(Rb, kb0, kb1, kb2, kb3);
      unsigned kc0 = pk_max(__builtin_fmaf(2.f, ac0[2], -sq0), jr0);
      unsigned kc1 = pk_max(__builtin_fmaf(2.f, ac1[2], -sq1), jr1);
      unsigned kc2 = pk_max(__builtin_fmaf(2.f, ac2[2], -sq2), jr2);
      unsigned kc3 = pk_max(__builtin_fmaf(2.f, ac3[2], -sq3), jr3);
      T8_B4_MAX(Rc, kc0, kc1, kc2, kc3);
      unsigned kd0 = pk_max(__builtin_fmaf(2.f, ac0[3], -sq0), jr0);
      unsigned kd1 = pk_max(__builtin_fmaf(2.f, ac1[3], -sq1), jr1);
      unsigned kd2 = pk_max(__builtin_fmaf(2.f, ac2[3], -sq2), jr2);
      unsigned kd3 = pk_max(__builtin_fmaf(2.f, ac3[3], -sq3), jr3);
      T8_B4_MAX(Rd, kd0, kd1, kd2, kd3);
    }
    if (pf) {
      bf16_t* bufn = bufs + ((jt + 1) & 1) * 8192;
      *(uint4*)&bufn[(trow     )*128 + swz*8] = g0;
      *(uint4*)&bufn[(trow + 32)*128 + swz*8] = g1;
    }
    __syncthreads();
  }
#undef BFR
  // butterfly merge across the 16 j-partitions (lane bits 0-3 = l16); no LDS
  T8_SHMERGE_MAX(Ra, 1) T8_SHMERGE_MAX(Ra, 2) T8_SHMERGE_MAX(Ra, 4) T8_SHMERGE_MAX(Ra, 8)
  T8_SHMERGE_MAX(Rb, 1) T8_SHMERGE_MAX(Rb, 2) T8_SHMERGE_MAX(Rb, 4) T8_SHMERGE_MAX(Rb, 8)
  T8_SHMERGE_MAX(Rc, 1) T8_SHMERGE_MAX(Rc, 2) T8_SHMERGE_MAX(Rc, 4) T8_SHMERGE_MAX(Rc, 8)
  T8_SHMERGE_MAX(Rd, 1) T8_SHMERGE_MAX(Rd, 2) T8_SHMERGE_MAX(Rd, 4) T8_SHMERGE_MAX(Rd, 8)
  if (l16 == 0) {
    const size_t rbase = ((size_t)b*NP + i0 + wv*16 + quad*4);
    unsigned* o = pkw + (rbase*JSEG + seg) * 8;
    o[0]=Ra0; o[1]=Ra1; o[2]=Ra2; o[3]=Ra3; o[4]=Ra4; o[5]=Ra5; o[6]=Ra6; o[7]=Ra7;
    o = pkw + ((rbase+1)*JSEG + seg) * 8;
    o[0]=Rb0; o[1]=Rb1; o[2]=Rb2; o[3]=Rb3; o[4]=Rb4; o[5]=Rb5; o[6]=Rb6; o[7]=Rb7;
    o = pkw + ((rbase+2)*JSEG + seg) * 8;
    o[0]=Rc0; o[1]=Rc1; o[2]=Rc2; o[3]=Rc3; o[4]=Rc4; o[5]=Rc5; o[6]=Rc6; o[7]=Rc7;
    o = pkw + ((rbase+3)*JSEG + seg) * 8;
    o[0]=Rd0; o[1]=Rd1; o[2]=Rd2; o[3]=Rd3; o[4]=Rd4; o[5]=Rd5; o[6]=Rd6; o[7]=Rd7;
  }
}

// ---------------- merge per-segment packed partials -> final indices ----------------
__global__ __launch_bounds__(256) void knn_merge_kernel(const unsigned* __restrict__ pkw,
                                                        int* __restrict__ idxo)
{
  const int row = blockIdx.x * 256 + threadIdx.x;   // < NB*NP
  const unsigned* q = pkw + (size_t)row * JSEG * 8;
  T8_DECL_MAX(F);
#pragma unroll
  for (int m = 0; m < JSEG * 8; ++m) { unsigned v = q[m]; T8_INS_MAX(F, v); }
  int* o = idxo + (size_t)row * 8;
  o[0] = 2047 - (int)(F0 & 0x7FFu); o[1] = 2047 - (int)(F1 & 0x7FFu);
  o[2] = 2047 - (int)(F2 & 0x7FFu); o[3] = 2047 - (int)(F3 & 0x7FFu);
  o[4] = 2047 - (int)(F4 & 0x7FFu); o[5] = 2047 - (int)(F5 & 0x7FFu);
  o[6] = 2047 - (int)(F6 & 0x7FFu); o[7] = 2047 - (int)(F7 & 0x7FFu);
}

// ---------------- edge MLP: barrier-free, all-register h1 fragments ----------------
__global__ __launch_bounds__(256, 2) void edge_mlp_kernel(
    const bf16_t* __restrict__ P, const bf16_t* __restrict__ Q, const int* __restrict__ idx,
    const bf16_t* __restrict__ W2T, const float* __restrict__ b2,
    bf16_t* __restrict__ xout, float* __restrict__ pooled, int poolOff)
{
  const int b = blockIdx.y;
  const size_t bNP = (size_t)b * NP;
  const int t = threadIdx.x;
  const int lane = t & 63, w = t >> 6, quad = lane >> 4, l16 = lane & 15;
  const int pbase = blockIdx.x * 64 + w * 16;
  const bf16_t* __restrict__ Wb = W2T + (size_t)l16 * HD + quad * 8;
#define LDB(ks, ct) const bf16x8 B##ks##ct = *(const bf16x8*)&Wb[ct*16*HD + ks*32];
  LDB(0,0) LDB(0,1) LDB(0,2) LDB(0,3) LDB(0,4) LDB(0,5) LDB(0,6) LDB(0,7)
  LDB(1,0) LDB(1,1) LDB(1,2) LDB(1,3) LDB(1,4) LDB(1,5) LDB(1,6) LDB(1,7)
#undef LDB
  const float bv0 = b2[  0 + l16], bv1 = b2[ 16 + l16], bv2 = b2[ 32 + l16], bv3 = b2[ 48 + l16];
  const float bv4 = b2[ 64 + l16], bv5 = b2[ 80 + l16], bv6 = b2[ 96 + l16], bv7 = b2[112 + l16];
  float pa0=0.f, pa1=0.f, pa2=0.f, pa3=0.f, pa4=0.f, pa5=0.f, pa6=0.f, pa7=0.f;
  const f32x4 z = {0.f, 0.f, 0.f, 0.f};
  for (int it = 0; it < 8; ++it) {
    const int ip = pbase + it*2 + (l16 >> 3);
    const int j = idx[(bNP + ip)*8 + (l16 & 7)];
    const bf16_t* Qr = Q + (bNP + (unsigned)j)*HD + quad*8;
    const bf16_t* Pr = P + (bNP + ip)*HD + quad*8;
    bf16x8 q0 = *(const bf16x8*)(Qr     );
    bf16x8 q1 = *(const bf16x8*)(Qr + 32);
    bf16x8 q2 = *(const bf16x8*)(Qr + 64);
    bf16x8 q3 = *(const bf16x8*)(Qr + 96);
    bf16x8 p0 = *(const bf16x8*)(Pr     );
    bf16x8 p1 = *(const bf16x8*)(Pr + 32);
    bf16x8 p2 = *(const bf16x8*)(Pr + 64);
    bf16x8 p3 = *(const bf16x8*)(Pr + 96);
    bf16x8 af0, af1, af2, af3;
#pragma unroll
    for (int k = 0; k < 8; ++k) {
      af0[k] = (bf16_t)fmaxf((float)p0[k] + (float)q0[k], 0.f);
      af1[k] = (bf16_t)fmaxf((float)p1[k] + (float)q1[k], 0.f);
      af2[k] = (bf16_t)fmaxf((float)p2[k] + (float)q2[k], 0.f);
      af3[k] = (bf16_t)fmaxf((float)p3[k] + (float)q3[k], 0.f);
    }
    f32x4 ac0=z, ac1=z, ac2=z, ac3=z, ac4=z, ac5=z, ac6=z, ac7=z;
    ac0 = __builtin_amdgcn_mfma_f32_16x16x32_bf16(af0, B00, ac0, 0,0,0);
    ac1 = __builtin_amdgcn_mfma_f32_16x16x32_bf16(af0, B01, ac1, 0,0,0);
    ac2 = __builtin_amdgcn_mfma_f32_16x16x32_bf16(af0, B02, ac2, 0,0,0);
    ac3 = __builtin_amdgcn_mfma_f32_16x16x32_bf16(af0, B03, ac3, 0,0,0);
    ac4 = __builtin_amdgcn_mfma_f32_16x16x32_bf16(af0, B04, ac4, 0,0,0);
    ac5 = __builtin_amdgcn_mfma_f32_16x16x32_bf16(af0, B05, ac5, 0,0,0);
    ac6 = __builtin_amdgcn_mfma_f32_16x16x32_bf16(af0, B06, ac6, 0,0,0);
    ac7 = __builtin_amdgcn_mfma_f32_16x16x32_bf16(af0, B07, ac7, 0,0,0);
    ac0 = __builtin_amdgcn_mfma_f32_16x16x32_bf16(af1, B10, ac0, 0,0,0);
    ac1 = __builtin_amdgcn_mfma_f32_16x16x32_bf16(af1, B11, ac1, 0,0,0);
    ac2 = __builtin_amdgcn_mfma_f32_16x16x32_bf16(af1, B12, ac2, 0,0,0);
    ac3 = __builtin_amdgcn_mfma_f32_16x16x32_bf16(af1, B13, ac3, 0,0,0);
    ac4 = __builtin_amdgcn_mfma_f32_16x16x32_bf16(af1, B14, ac4, 0,0,0);
    ac5 = __builtin_amdgcn_mfma_f32_16x16x32_bf16(af1, B15, ac5, 0,0,0);
    ac6 = __builtin_amdgcn_mfma_f32_16x16x32_bf16(af1, B16, ac6, 0,0,0);
    ac7 = __builtin_amdgcn_mfma_f32_16x16x32_bf16(af1, B17, ac7, 0,0,0);
#define MM2(ct, accv) { \
    bf16x8 b2f = *(const bf16x8*)&Wb[ct*16*HD + 2*32]; \
    accv = __builtin_amdgcn_mfma_f32_16x16x32_bf16(af2, b2f, accv, 0,0,0); \
    bf16x8 b3f = *(const bf16x8*)&Wb[ct*16*HD + 3*32]; \
    accv = __builtin_amdgcn_mfma_f32_16x16x32_bf16(af3, b3f, accv, 0,0,0); }
    MM2(0, ac0) MM2(1, ac1) MM2(2, ac2) MM2(3, ac3)
    MM2(4, ac4) MM2(5, ac5) MM2(6, ac6) MM2(7, ac7)
#undef MM2
    const int ipt = pbase + it*2 + (quad >> 1);
    bf16_t* xr = xout + (bNP + ipt)*HD + l16;
#define EPI(ct, accv, bvv, pav) { \
    float s = fmaxf(accv[0]+bvv,0.f) + fmaxf(accv[1]+bvv,0.f) \
            + fmaxf(accv[2]+bvv,0.f) + fmaxf(accv[3]+bvv,0.f); \
    s += __shfl_xor(s, 16); \
    if ((quad & 1) == 0) xr[ct*16] = (bf16_t)(s * 0.125f); \
    pav += s + __shfl_xor(s, 32); }
    EPI(0, ac0, bv0, pa0) EPI(1, ac1, bv1, pa1) EPI(2, ac2, bv2, pa2) EPI(3, ac3, bv3, pa3)
    EPI(4, ac4, bv4, pa4) EPI(5, ac5, bv5, pa5) EPI(6, ac6, bv6, pa6) EPI(7, ac7, bv7, pa7)
#undef EPI
  }
  if (quad == 0) {
    float* pr = pooled + b*384 + poolOff + l16;
    atomicAdd(pr +   0, pa0 * 0.125f);
    atomicAdd(pr +  16, pa1 * 0.125f);
    atomicAdd(pr +  32, pa2 * 0.125f);
    atomicAdd(pr +  48, pa3 * 0.125f);
    atomicAdd(pr +  64, pa4 * 0.125f);
    atomicAdd(pr +  80, pa5 * 0.125f);
    atomicAdd(pr +  96, pa6 * 0.125f);
    atomicAdd(pr + 112, pa7 * 0.125f);
  }
}

// ---------------- final pooled MLP ----------------
__global__ __launch_bounds__(128) void final_mlp_kernel(
    const float* __restrict__ pooled, const float* __restrict__ W1, const float* __restrict__ b1v,
    const float* __restrict__ W2, const float* __restrict__ b2v, float* __restrict__ out)
{
  __shared__ float hb[128];
  int b = blockIdx.x, g = threadIdx.x;
  float h = b1v[g];
  const float inv = 1.0f / (float)NP;
  for (int c = 0; c < 384; ++c) h += pooled[b*384 + c] * inv * W1[c*128 + g];
  hb[g] = fmaxf(h, 0.f);
  __syncthreads();
  if (g < 2) {
    float o = b2v[g];
    for (int k2 = 0; k2 < 128; ++k2) o += hb[k2] * W2[k2*2 + g];
    out[b*2 + g] = o;
  }
}

extern "C" void kernel_launch(void* const* d_in, const int* in_sizes, int n_in,
                              void* d_out, int out_size, void* d_ws, size_t ws_size,
                              hipStream_t stream) {
  (void)in_sizes; (void)n_in; (void)out_size; (void)ws_size;
  const float* x    = (const float*)d_in[0];
  const float* c1W1 = (const float*)d_in[1];
  const float* c1b1 = (const float*)d_in[2];
  const float* c1W2 = (const float*)d_in[3];
  const float* c1b2 = (const float*)d_in[4];
  const float* c2W1 = (const float*)d_in[5];
  const float* c2b1 = (const float*)d_in[6];
  const float* c2W2 = (const float*)d_in[7];
  const float* c2b2 = (const float*)d_in[8];
  const float* c3W1 = (const float*)d_in[9];
  const float* c3b1 = (const float*)d_in[10];
  const float* c3W2 = (const float*)d_in[11];
  const float* c3b2 = (const float*)d_in[12];
  const float* mW1  = (const float*)d_in[13];
  const float* mb1  = (const float*)d_in[14];
  const float* mW2  = (const float*)d_in[15];
  const float* mb2  = (const float*)d_in[16];

  char* wsp = (char*)d_ws;
  auto carve = [&](size_t bytes) -> void* {
    void* p = (void*)wsp; wsp += (bytes + 255) & ~(size_t)255; return p;
  };
  bf16_t* x1b  = (bf16_t*)carve((size_t)NB*NP*HD*2);
  bf16_t* x2b  = (bf16_t*)carve((size_t)NB*NP*HD*2);
  bf16_t* x3b  = (bf16_t*)carve((size_t)NB*NP*HD*2);
  bf16_t* Pbuf = (bf16_t*)carve((size_t)NB*NP*HD*2);
  bf16_t* Qbuf = (bf16_t*)carve((size_t)NB*NP*HD*2);
  float*  sqb  = (float*)carve((size_t)NB*NP*4);
  int*    idxb = (int*)carve((size_t)NB*NP*8*4);
  unsigned* pkw = (unsigned*)carve((size_t)NB*NP*JSEG*8*4);
  bf16_t* W2T1 = (bf16_t*)carve(128*128*2);
  bf16_t* WpT2 = (bf16_t*)carve(128*128*2);
  bf16_t* WqT2 = (bf16_t*)carve(128*128*2);
  bf16_t* W2T2 = (bf16_t*)carve(128*128*2);
  bf16_t* WpT3 = (bf16_t*)carve(128*128*2);
  bf16_t* WqT3 = (bf16_t*)carve(128*128*2);
  bf16_t* W2T3 = (bf16_t*)carve(128*128*2);
  float*  pooled = (float*)carve((size_t)NB*384*4);

  hipMemsetAsync(pooled, 0, (size_t)NB*384*4, stream);
  wprep_kernel<<<448, 256, 0, stream>>>(c1W2, c2W1, c2W2, c3W1, c3W2,
                                        W2T1, WpT2, WqT2, W2T2, WpT3, WqT3, W2T3);
  // layer 1
  pq1_kernel<<<4096, 256, 0, stream>>>(x, c1W1, c1b1, Pbuf, Qbuf);
  knn1_kernel<<<dim3(NP/32, NB), 256, 0, stream>>>(x, idxb);
  edge_mlp_kernel<<<dim3(NP/64, NB), 256, 0, stream>>>(Pbuf, Qbuf, idxb, W2T1, c1b2, x1b, pooled, 0);
  // layer 2
  prep_sq_kernel<<<128, 256, 0, stream>>>(x1b, sqb);
  pq_gemm_kernel<<<dim3(NB*NP/128, 2), 256, 0, stream>>>(x1b, WpT2, WqT2, c2b1, Pbuf, Qbuf);
  knn_big_kernel<<<dim3(NP/128, NB, JSEG), 512, 0, stream>>>(x1b, sqb, pkw);
  knn_merge_kernel<<<NB*NP/256, 256, 0, stream>>>(pkw, idxb);
  edge_mlp_kernel<<<dim3(NP/64, NB), 256, 0, stream>>>(Pbuf, Qbuf, idxb, W2T2, c2b2, x2b, pooled, 128);
  // layer 3
  prep_sq_kernel<<<128, 256, 0, stream>>>(x2b, sqb);
  pq_gemm_kernel<<<dim3(NB*NP/128, 2), 256, 0, stream>>>(x2b, WpT3, WqT3, c3b1, Pbuf, Qbuf);
  knn_big_kernel<<<dim3(NP/128, NB, JSEG), 512, 0, stream>>>(x2b, sqb, pkw);
  knn_merge_kernel<<<NB*NP/256, 256, 0, stream>>>(pkw, idxb);
  edge_mlp_kernel<<<dim3(NP/64, NB), 256, 0, stream>>>(Pbuf, Qbuf, idxb, W2T3, c3b2, x3b, pooled, 256);
  // head
  final_mlp_kernel<<<NB, 128, 0, stream>>>(pooled, mW1, mb1, mW2, mb2, (float*)d_out);
}

// Round 15
// 361.937 us; speedup vs baseline: 1.0634x; 1.0153x over previous
//
#include <hip/hip_runtime.h>

#define NB 16
#define NP 2048
#define HD 128
#define LDP 136   // padded LDS row (bf16 elems)
#define JSEG 2    // j-range split for knn_big (2 is measured optimum)

typedef __bf16 bf16_t;
typedef bf16_t bf16x8 __attribute__((ext_vector_type(8)));
typedef bf16_t bf16x4 __attribute__((ext_vector_type(4)));
typedef float  f32x4  __attribute__((ext_vector_type(4)));

// ---------------- packed-key top-8 machinery ----------------
__device__ __forceinline__ unsigned pk_max(float k, unsigned jrev) {
  unsigned u = __float_as_uint(k);
  unsigned s = u ^ (unsigned)(((int)u >> 31) | 0x80000000);
  return (s & 0xFFFFF800u) | jrev;
}
__device__ __forceinline__ unsigned pk_min(float k, unsigned j) {
  unsigned u = __float_as_uint(k);
  unsigned s = u ^ (unsigned)(((int)u >> 31) | 0x80000000);
  return (s & 0xFFFFF800u) | j;
}

#define T8_DECL_MAX(p) unsigned p##0=0u,p##1=0u,p##2=0u,p##3=0u,p##4=0u,p##5=0u,p##6=0u,p##7=0u
#define T8_STEP_MAX(b,cc) { unsigned t_ = ((b)<(cc)?(b):(cc)); (b) = ((b)>(cc)?(b):(cc)); (cc) = t_; }
#define T8_INS_MAX(p,c) { unsigned cc_=(c); \
  T8_STEP_MAX(p##0,cc_) T8_STEP_MAX(p##1,cc_) T8_STEP_MAX(p##2,cc_) T8_STEP_MAX(p##3,cc_) \
  T8_STEP_MAX(p##4,cc_) T8_STEP_MAX(p##5,cc_) T8_STEP_MAX(p##6,cc_) T8_STEP_MAX(p##7,cc_) }
#define T8_GINS_MAX(p,c) { unsigned cg_=(c); if (cg_ > p##7) { T8_INS_MAX(p, cg_) } }

#define T8_DECL_MIN(p) unsigned p##0=0xFFFFFFFFu,p##1=0xFFFFFFFFu,p##2=0xFFFFFFFFu,p##3=0xFFFFFFFFu,p##4=0xFFFFFFFFu,p##5=0xFFFFFFFFu,p##6=0xFFFFFFFFu,p##7=0xFFFFFFFFu
#define T8_STEP_MIN(b,cc) { unsigned t_ = ((b)>(cc)?(b):(cc)); (b) = ((b)<(cc)?(b):(cc)); (cc) = t_; }
#define T8_INS_MIN(p,c) { unsigned cc_=(c); \
  T8_STEP_MIN(p##0,cc_) T8_STEP_MIN(p##1,cc_) T8_STEP_MIN(p##2,cc_) T8_STEP_MIN(p##3,cc_) \
  T8_STEP_MIN(p##4,cc_) T8_STEP_MIN(p##5,cc_) T8_STEP_MIN(p##6,cc_) T8_STEP_MIN(p##7,cc_) }
#define T8_GINS_MIN(p,c) { unsigned cg_=(c); if (cg_ < p##7) { T8_INS_MIN(p, cg_) } }

// ---- batched bitonic top-8 update (exact, branchless; faiss-style) ----
#define CMPX_DESC(a,b) { unsigned h_=((a)>(b)?(a):(b)); unsigned l_=((a)<(b)?(a):(b)); (a)=h_; (b)=l_; }
#define CMPX_ASC(a,b)  { unsigned l_=((a)<(b)?(a):(b)); unsigned h_=((a)>(b)?(a):(b)); (a)=l_; (b)=h_; }

#define T8_B4_MAX(p, d0,d1,d2,d3) { \
  unsigned x0_=(d0), x1_=(d1), x2_=(d2), x3_=(d3); \
  CMPX_DESC(x0_,x1_) CMPX_DESC(x2_,x3_) CMPX_DESC(x0_,x2_) CMPX_DESC(x1_,x3_) CMPX_DESC(x1_,x2_) \
  p##4 = p##4 > x3_ ? p##4 : x3_; \
  p##5 = p##5 > x2_ ? p##5 : x2_; \
  p##6 = p##6 > x1_ ? p##6 : x1_; \
  p##7 = p##7 > x0_ ? p##7 : x0_; \
  CMPX_DESC(p##0,p##4) CMPX_DESC(p##1,p##5) CMPX_DESC(p##2,p##6) CMPX_DESC(p##3,p##7) \
  CMPX_DESC(p##0,p##2) CMPX_DESC(p##1,p##3) CMPX_DESC(p##4,p##6) CMPX_DESC(p##5,p##7) \
  CMPX_DESC(p##0,p##1) CMPX_DESC(p##2,p##3) CMPX_DESC(p##4,p##5) CMPX_DESC(p##6,p##7) }

#define T8_B4_MIN(p, d0,d1,d2,d3) { \
  unsigned x0_=(d0), x1_=(d1), x2_=(d2), x3_=(d3); \
  CMPX_ASC(x0_,x1_) CMPX_ASC(x2_,x3_) CMPX_ASC(x0_,x2_) CMPX_ASC(x1_,x3_) CMPX_ASC(x1_,x2_) \
  p##4 = p##4 < x3_ ? p##4 : x3_; \
  p##5 = p##5 < x2_ ? p##5 : x2_; \
  p##6 = p##6 < x1_ ? p##6 : x1_; \
  p##7 = p##7 < x0_ ? p##7 : x0_; \
  CMPX_ASC(p##0,p##4) CMPX_ASC(p##1,p##5) CMPX_ASC(p##2,p##6) CMPX_ASC(p##3,p##7) \
  CMPX_ASC(p##0,p##2) CMPX_ASC(p##1,p##3) CMPX_ASC(p##4,p##6) CMPX_ASC(p##5,p##7) \
  CMPX_ASC(p##0,p##1) CMPX_ASC(p##2,p##3) CMPX_ASC(p##4,p##5) CMPX_ASC(p##6,p##7) }

// ---- shuffle butterfly merge: merge own sorted-8(desc) with lane^mask partner's ----
#define T8_SHMERGE_MAX(p, mask) { \
  unsigned o_; \
  o_ = (unsigned)__shfl_xor((int)p##7, mask); p##0 = p##0 > o_ ? p##0 : o_; \
  o_ = (unsigned)__shfl_xor((int)p##6, mask); p##1 = p##1 > o_ ? p##1 : o_; \
  o_ = (unsigned)__shfl_xor((int)p##5, mask); p##2 = p##2 > o_ ? p##2 : o_; \
  o_ = (unsigned)__shfl_xor((int)p##4, mask); p##3 = p##3 > o_ ? p##3 : o_; \
  o_ = (unsigned)__shfl_xor((int)p##3, mask); p##4 = p##4 > o_ ? p##4 : o_; \
  o_ = (unsigned)__shfl_xor((int)p##2, mask); p##5 = p##5 > o_ ? p##5 : o_; \
  o_ = (unsigned)__shfl_xor((int)p##1, mask); p##6 = p##6 > o_ ? p##6 : o_; \
  o_ = (unsigned)__shfl_xor((int)p##0, mask); p##7 = p##7 > o_ ? p##7 : o_; \
  CMPX_DESC(p##0,p##4) CMPX_DESC(p##1,p##5) CMPX_DESC(p##2,p##6) CMPX_DESC(p##3,p##7) \
  CMPX_DESC(p##0,p##2) CMPX_DESC(p##1,p##3) CMPX_DESC(p##4,p##6) CMPX_DESC(p##5,p##7) \
  CMPX_DESC(p##0,p##1) CMPX_DESC(p##2,p##3) CMPX_DESC(p##4,p##5) CMPX_DESC(p##6,p##7) }

// ---------------- weight prep + pooled zero-init (block 448) ----------------
__global__ __launch_bounds__(256) void wprep_kernel(
    const float* __restrict__ c1W2, const float* __restrict__ c2W1, const float* __restrict__ c2W2,
    const float* __restrict__ c3W1, const float* __restrict__ c3W2,
    bf16_t* __restrict__ W2T1, bf16_t* __restrict__ WpT2, bf16_t* __restrict__ WqT2,
    bf16_t* __restrict__ W2T2, bf16_t* __restrict__ WpT3, bf16_t* __restrict__ WqT3,
    bf16_t* __restrict__ W2T3, float* __restrict__ pooled)
{
  if (blockIdx.x == 448) {                      // zero pooled (NB*384 = 6144 floats)
    for (int u = threadIdx.x; u < NB*384; u += 256) pooled[u] = 0.f;
    return;
  }
  int tid = blockIdx.x * 256 + threadIdx.x;     // < 7*16384
  int m = tid >> 14, e = tid & 16383;
  int r = e >> 7, c = e & 127;
  switch (m) {
    case 0: W2T1[r*128+c] = (bf16_t)c1W2[c*128+r]; break;
    case 1: WpT2[r*128+c] = (bf16_t)(c2W1[c*128+r] - c2W1[(128+c)*128+r]); break;
    case 2: WqT2[r*128+c] = (bf16_t)c2W1[(128+c)*128+r]; break;
    case 3: W2T2[r*128+c] = (bf16_t)c2W2[c*128+r]; break;
    case 4: WpT3[r*128+c] = (bf16_t)(c3W1[c*128+r] - c3W1[(128+c)*128+r]); break;
    case 5: WqT3[r*128+c] = (bf16_t)c3W1[(128+c)*128+r]; break;
    case 6: W2T3[r*128+c] = (bf16_t)c3W2[c*128+r]; break;
  }
}

// ---------------- layer-1 P/Q (bf16 out) ----------------
__global__ __launch_bounds__(256) void pq1_kernel(
    const float* __restrict__ x, const float* __restrict__ W1, const float* __restrict__ b1,
    bf16_t* __restrict__ P, bf16_t* __restrict__ Q)
{
  int tid = blockIdx.x * 256 + threadIdx.x;     // < 32768*32
  int row = tid >> 5, c0 = (tid & 31) * 4;
  float x0 = x[row*3+0], x1 = x[row*3+1], x2 = x[row*3+2];
  bf16x4 pv, qv;
#pragma unroll
  for (int u = 0; u < 4; ++u) {
    int c = c0 + u;
    float wq0 = W1[3*128+c], wq1 = W1[4*128+c], wq2 = W1[5*128+c];
    float wp0 = W1[0*128+c]-wq0, wp1 = W1[1*128+c]-wq1, wp2 = W1[2*128+c]-wq2;
    pv[u] = (bf16_t)(x0*wp0 + x1*wp1 + x2*wp2 + b1[c]);
    qv[u] = (bf16_t)(x0*wq0 + x1*wq1 + x2*wq2);
  }
  *(bf16x4*)&P[(size_t)row*HD + c0] = pv;
  *(bf16x4*)&Q[(size_t)row*HD + c0] = qv;
}

// ---------------- kNN layer 1 (32 rows/block, 8 partitions, batched bitonic top-8) ----------------
__global__ __launch_bounds__(256) void knn1_kernel(const float* __restrict__ x, int* __restrict__ idxo)
{
  __shared__ __align__(16) float4 pts[NP];      // 32 KB: (x, y, z, |x|^2)
  __shared__ unsigned mrg[32 * 64];             // 8 KB merge scratch (packed keys)
  const int b = blockIdx.y, i0 = blockIdx.x * 32;
  const int t = threadIdx.x;
  const float* __restrict__ xb = x + (size_t)b * NP * 3;
  for (int u = t; u < NP; u += 256) {
    float a0 = xb[u*3+0], a1 = xb[u*3+1], a2 = xb[u*3+2];
    pts[u] = make_float4(a0, a1, a2, a0*a0 + a1*a1 + a2*a2);
  }
  __syncthreads();
  const int selr = t >> 3, selp = t & 7;        // 32 rows x 8 partitions
  const float4 pi = pts[i0 + selr];
  T8_DECL_MIN(L);
#pragma unroll 2
  for (int jj = 0; jj < NP / 32; ++jj) {
    const int jb = jj * 32 + selp;
    float4 p0 = pts[jb];
    float4 p1 = pts[jb + 8];
    float4 p2 = pts[jb + 16];
    float4 p3 = pts[jb + 24];
    float k0 = p0.w - 2.0f * (p0.x*pi.x + p0.y*pi.y + p0.z*pi.z);
    float k1 = p1.w - 2.0f * (p1.x*pi.x + p1.y*pi.y + p1.z*pi.z);
    float k2 = p2.w - 2.0f * (p2.x*pi.x + p2.y*pi.y + p2.z*pi.z);
    float k3 = p3.w - 2.0f * (p3.x*pi.x + p3.y*pi.y + p3.z*pi.z);
    T8_B4_MIN(L, pk_min(k0, (unsigned)jb), pk_min(k1, (unsigned)(jb+8)),
                 pk_min(k2, (unsigned)(jb+16)), pk_min(k3, (unsigned)(jb+24)));
  }
  {
    unsigned* e = &mrg[selr*64 + selp*8];
    e[0]=L0; e[1]=L1; e[2]=L2; e[3]=L3; e[4]=L4; e[5]=L5; e[6]=L6; e[7]=L7;
  }
  __syncthreads();
  if (t < 32) {
    T8_DECL_MIN(F);
    const unsigned* q = &mrg[t*64];
#pragma unroll
    for (int m = 0; m < 64; ++m) { unsigned v = q[m]; T8_GINS_MIN(F, v); }
    int* o = idxo + ((size_t)b*NP + i0 + t) * 8;
    o[0] = (int)(F0 & 0x7FFu); o[1] = (int)(F1 & 0x7FFu);
    o[2] = (int)(F2 & 0x7FFu); o[3] = (int)(F3 & 0x7FFu);
    o[4] = (int)(F4 & 0x7FFu); o[5] = (int)(F5 & 0x7FFu);
    o[6] = (int)(F6 & 0x7FFu); o[7] = (int)(F7 & 0x7FFu);
  }
}

// ---------------- P/Q GEMM for layers 2/3 (bf16 out) + fused row norms ----------------
// isP blocks also compute sqg for their 128 rows from the staged At tile, with the SAME
// sequential c-order accumulation as the old prep_sq kernel -> bit-identical sq values.
__global__ __launch_bounds__(256) void pq_gemm_kernel(
    const bf16_t* __restrict__ X, const bf16_t* __restrict__ WpT, const bf16_t* __restrict__ WqT,
    const float* __restrict__ b1, bf16_t* __restrict__ P, bf16_t* __restrict__ Q,
    float* __restrict__ sqg)
{
  __shared__ __align__(16) bf16_t At[128 * LDP];
  const int r0 = blockIdx.x * 128;
  const bool isP = (blockIdx.y == 0);
  const bf16_t* __restrict__ WT = isP ? WpT : WqT;
  bf16_t* __restrict__ Out = isP ? P : Q;
  const int t = threadIdx.x;
  for (int u = t; u < 2048; u += 256) {
    int r = u >> 4, c = (u & 15) * 8;
    *(bf16x8*)&At[r*LDP + c] = *(const bf16x8*)&X[(size_t)(r0 + r)*HD + c];
  }
  __syncthreads();
  if (isP && t < 128) {                         // fused prep_sq (sequential order preserved)
    const bf16_t* row = &At[t * LDP];
    float s = 0.f;
#pragma unroll
    for (int c = 0; c < HD; c += 8) {
      bf16x8 v = *(const bf16x8*)&row[c];
#pragma unroll
      for (int q = 0; q < 8; ++q) { float f = (float)v[q]; s += f * f; }
    }
    sqg[r0 + t] = s;
  }
  const int lane = t & 63, w = t >> 6, quad = lane >> 4, l16 = lane & 15;
  f32x4 acc[2][8];
  f32x4 z = {0.f, 0.f, 0.f, 0.f};
#pragma unroll
  for (int rt = 0; rt < 2; ++rt)
#pragma unroll
    for (int ct = 0; ct < 8; ++ct) acc[rt][ct] = z;
#pragma unroll
  for (int ks = 0; ks < 4; ++ks) {
    const int kk = ks*32 + quad*8;
    bf16x8 a0 = *(const bf16x8*)&At[(w*32 + l16)*LDP + kk];
    bf16x8 a1 = *(const bf16x8*)&At[(w*32 + 16 + l16)*LDP + kk];
#pragma unroll
    for (int ct = 0; ct < 8; ++ct) {
      bf16x8 bb = *(const bf16x8*)&WT[(ct*16 + l16)*HD + kk];
      acc[0][ct] = __builtin_amdgcn_mfma_f32_16x16x32_bf16(a0, bb, acc[0][ct], 0, 0, 0);
      acc[1][ct] = __builtin_amdgcn_mfma_f32_16x16x32_bf16(a1, bb, acc[1][ct], 0, 0, 0);
    }
  }
#pragma unroll
  for (int rt = 0; rt < 2; ++rt)
#pragma unroll
    for (int ct = 0; ct < 8; ++ct) {
      float bv = isP ? b1[ct*16 + l16] : 0.f;
#pragma unroll
      for (int r = 0; r < 4; ++r) {
        int row = w*32 + rt*16 + quad*4 + r;
        Out[(size_t)(r0 + row)*HD + ct*16 + l16] = (bf16_t)(acc[rt][ct][r] + bv);
      }
    }
}

// ---------------- fused Gram(MFMA) + bitonic top-8; 8 waves share B-tile; shfl merge ----------------
__global__ __launch_bounds__(512, 4) void knn_big_kernel(
    const bf16_t* __restrict__ X, const float* __restrict__ sqg, unsigned* __restrict__ pkw)
{
  __shared__ __align__(16) unsigned shm[9216];  // [0,8192): two B-buffers; [8192,9216): sq
  const int b = blockIdx.y, i0 = blockIdx.x * 128, seg = blockIdx.z;
  const int jbase = seg * (NP / JSEG);
  const int NT = (NP / JSEG) / 64;              // 16 j-tiles per segment
  const int t = threadIdx.x;
  const bf16_t* __restrict__ Xb = X + (size_t)b * NP * HD;
  const float* __restrict__ sqb = sqg + (size_t)b * NP + jbase;
  for (int u = t; u < NP / JSEG; u += 512) shm[8192 + u] = __float_as_uint(sqb[u]);
  const int lane = t & 63, wv = t >> 6, quad = lane >> 4, l16 = lane & 15;
  const int sw = l16 & 7;
  const bf16_t* Ar = Xb + (size_t)(i0 + wv*16 + l16)*HD + quad*8;
  bf16x8 af0 = *(const bf16x8*)(Ar);
  bf16x8 af1 = *(const bf16x8*)(Ar + 32);
  bf16x8 af2 = *(const bf16x8*)(Ar + 64);
  bf16x8 af3 = *(const bf16x8*)(Ar + 96);
  const int trow = t >> 4, gcol = t & 15;       // trow in [0,32)
  const int swz = gcol ^ (trow & 7);            // (trow+32)&7 == trow&7
  const bf16_t* gs = Xb + (size_t)(jbase + trow)*HD + gcol*8;
  bf16_t* const bufs = (bf16_t*)shm;
  {
    uint4 g0 = *(const uint4*)(gs);
    uint4 g1 = *(const uint4*)(gs + 32*HD);
    *(uint4*)&bufs[(trow     )*128 + swz*8] = g0;
    *(uint4*)&bufs[(trow + 32)*128 + swz*8] = g1;
  }
  T8_DECL_MAX(Ra); T8_DECL_MAX(Rb); T8_DECL_MAX(Rc); T8_DECL_MAX(Rd);
  __syncthreads();
  const f32x4 z = {0.f, 0.f, 0.f, 0.f};
  const unsigned jrb = 2047u - (unsigned)l16 - (unsigned)jbase;
#define BFR(ct, ks) (*(const bf16x8*)&bufc[(ct*16 + l16)*128 + (((ks*4 + quad) ^ sw) << 3)])
  for (int jt = 0; jt < NT; ++jt) {
    const int j0 = jt * 64;
    const bf16_t* bufc = bufs + (jt & 1) * 8192;
    uint4 g0, g1;
    const bool pf = (jt + 1 < NT);
    if (pf) {
      const bf16_t* gn = gs + (size_t)(jt + 1) * 64 * HD;
      g0 = *(const uint4*)(gn);
      g1 = *(const uint4*)(gn + 32*HD);
    }
    f32x4 ac0 = z, ac1 = z, ac2 = z, ac3 = z;
    ac0 = __builtin_amdgcn_mfma_f32_16x16x32_bf16(af0, BFR(0,0), ac0, 0,0,0);
    ac1 = __builtin_amdgcn_mfma_f32_16x16x32_bf16(af0, BFR(1,0), ac1, 0,0,0);
    ac2 = __builtin_amdgcn_mfma_f32_16x16x32_bf16(af0, BFR(2,0), ac2, 0,0,0);
    ac3 = __builtin_amdgcn_mfma_f32_16x16x32_bf16(af0, BFR(3,0), ac3, 0,0,0);
    ac0 = __builtin_amdgcn_mfma_f32_16x16x32_bf16(af1, BFR(0,1), ac0, 0,0,0);
    ac1 = __builtin_amdgcn_mfma_f32_16x16x32_bf16(af1, BFR(1,1), ac1, 0,0,0);
    ac2 = __builtin_amdgcn_mfma_f32_16x16x32_bf16(af1, BFR(2,1), ac2, 0,0,0);
    ac3 = __builtin_amdgcn_mfma_f32_16x16x32_bf16(af1, BFR(3,1), ac3, 0,0,0);
    ac0 = __builtin_amdgcn_mfma_f32_16x16x32_bf16(af2, BFR(0,2), ac0, 0,0,0);
    ac1 = __builtin_amdgcn_mfma_f32_16x16x32_bf16(af2, BFR(1,2), ac1, 0,0,0);
    ac2 = __builtin_amdgcn_mfma_f32_16x16x32_bf16(af2, BFR(2,2), ac2, 0,0,0);
    ac3 = __builtin_amdgcn_mfma_f32_16x16x32_bf16(af2, BFR(3,2), ac3, 0,0,0);
    ac0 = __builtin_amdgcn_mfma_f32_16x16x32_bf16(af3, BFR(0,3), ac0, 0,0,0);
    ac1 = __builtin_amdgcn_mfma_f32_16x16x32_bf16(af3, BFR(1,3), ac1, 0,0,0);
    ac2 = __builtin_amdgcn_mfma_f32_16x16x32_bf16(af3, BFR(2,3), ac2, 0,0,0);
    ac3 = __builtin_amdgcn_mfma_f32_16x16x32_bf16(af3, BFR(3,3), ac3, 0,0,0);
    const float sq0 = __uint_as_float(shm[8192 + j0      + l16]);
    const float sq1 = __uint_as_float(shm[8192 + j0 + 16 + l16]);
    const float sq2 = __uint_as_float(shm[8192 + j0 + 32 + l16]);
    const float sq3 = __uint_as_float(shm[8192 + j0 + 48 + l16]);
    const unsigned jr0 = jrb - (unsigned)j0;
    const unsigned jr1 = jr0 - 16u, jr2 = jr0 - 32u, jr3 = jr0 - 48u;
    {
      unsigned ka0 = pk_max(__builtin_fmaf(2.f, ac0[0], -sq0), jr0);
      unsigned ka1 = pk_max(__builtin_fmaf(2.f, ac1[0], -sq1), jr1);
      unsigned ka2 = pk_max(__builtin_fmaf(2.f, ac2[0], -sq2), jr2);
      unsigned ka3 = pk_max(__builtin_fmaf(2.f, ac3[0], -sq3), jr3);
      T8_B4_MAX(Ra, ka0, ka1, ka2, ka3);
      unsigned kb0 = pk_max(__builtin_fmaf(2.f, ac0[1], -sq0), jr0);
      unsigned kb1 = pk_max(__builtin_fmaf(2.f, ac1[1], -sq1), jr1);
      unsigned kb2 = pk_max(__builtin_fmaf(2.f, ac2[1], -sq2), jr2);
      unsigned kb3 = pk_max(__builtin_fmaf(2.f, ac3[1], -sq3), jr3);
      T8_B4_MAX(Rb, kb0, kb1, kb2, kb3);
      unsigned kc0 = pk_max(__builtin_fmaf(2.f, ac0[2], -sq0), jr0);
      unsigned kc1 = pk_max(__builtin_fmaf(2.f, ac1[2], -sq1), jr1);
      unsigned kc2 = pk_max(__builtin_fmaf(2.f, ac2[2], -sq2), jr2);
      unsigned kc3 = pk_max(__builtin_fmaf(2.f, ac3[2], -sq3), jr3);
      T8_B4_MAX(Rc, kc0, kc1, kc2, kc3);
      unsigned kd0 = pk_max(__builtin_fmaf(2.f, ac0[3], -sq0), jr0);
      unsigned kd1 = pk_max(__builtin_fmaf(2.f, ac1[3], -sq1), jr1);
      unsigned kd2 = pk_max(__builtin_fmaf(2.f, ac2[3], -sq2), jr2);
      unsigned kd3 = pk_max(__builtin_fmaf(2.f, ac3[3], -sq3), jr3);
      T8_B4_MAX(Rd, kd0, kd1, kd2, kd3);
    }
    if (pf) {
      bf16_t* bufn = bufs + ((jt + 1) & 1) * 8192;
      *(uint4*)&bufn[(trow     )*128 + swz*8] = g0;
      *(uint4*)&bufn[(trow + 32)*128 + swz*8] = g1;
    }
    __syncthreads();
  }
#undef BFR
  // butterfly merge across the 16 j-partitions (lane bits 0-3 = l16); no LDS
  T8_SHMERGE_MAX(Ra, 1) T8_SHMERGE_MAX(Ra, 2) T8_SHMERGE_MAX(Ra, 4) T8_SHMERGE_MAX(Ra, 8)
  T8_SHMERGE_MAX(Rb, 1) T8_SHMERGE_MAX(Rb, 2) T8_SHMERGE_MAX(Rb, 4) T8_SHMERGE_MAX(Rb, 8)
  T8_SHMERGE_MAX(Rc, 1) T8_SHMERGE_MAX(Rc, 2) T8_SHMERGE_MAX(Rc, 4) T8_SHMERGE_MAX(Rc, 8)
  T8_SHMERGE_MAX(Rd, 1) T8_SHMERGE_MAX(Rd, 2) T8_SHMERGE_MAX(Rd, 4) T8_SHMERGE_MAX(Rd, 8)
  if (l16 == 0) {
    const size_t rbase = ((size_t)b*NP + i0 + wv*16 + quad*4);
    unsigned* o = pkw + (rbase*JSEG + seg) * 8;
    o[0]=Ra0; o[1]=Ra1; o[2]=Ra2; o[3]=Ra3; o[4]=Ra4; o[5]=Ra5; o[6]=Ra6; o[7]=Ra7;
    o = pkw + ((rbase+1)*JSEG + seg) * 8;
    o[0]=Rb0; o[1]=Rb1; o[2]=Rb2; o[3]=Rb3; o[4]=Rb4; o[5]=Rb5; o[6]=Rb6; o[7]=Rb7;
    o = pkw + ((rbase+2)*JSEG + seg) * 8;
    o[0]=Rc0; o[1]=Rc1; o[2]=Rc2; o[3]=Rc3; o[4]=Rc4; o[5]=Rc5; o[6]=Rc6; o[7]=Rc7;
    o = pkw + ((rbase+3)*JSEG + seg) * 8;
    o[0]=Rd0; o[1]=Rd1; o[2]=Rd2; o[3]=Rd3; o[4]=Rd4; o[5]=Rd5; o[6]=Rd6; o[7]=Rd7;
  }
}

// ---------------- merge per-segment packed partials -> final indices ----------------
__global__ __launch_bounds__(256) void knn_merge_kernel(const unsigned* __restrict__ pkw,
                                                        int* __restrict__ idxo)
{
  const int row = blockIdx.x * 256 + threadIdx.x;   // < NB*NP
  const unsigned* q = pkw + (size_t)row * JSEG * 8;
  T8_DECL_MAX(F);
#pragma unroll
  for (int m = 0; m < JSEG * 8; ++m) { unsigned v = q[m]; T8_INS_MAX(F, v); }
  int* o = idxo + (size_t)row * 8;
  o[0] = 2047 - (int)(F0 & 0x7FFu); o[1] = 2047 - (int)(F1 & 0x7FFu);
  o[2] = 2047 - (int)(F2 & 0x7FFu); o[3] = 2047 - (int)(F3 & 0x7FFu);
  o[4] = 2047 - (int)(F4 & 0x7FFu); o[5] = 2047 - (int)(F5 & 0x7FFu);
  o[6] = 2047 - (int)(F6 & 0x7FFu); o[7] = 2047 - (int)(F7 & 0x7FFu);
}

// ---------------- edge MLP: barrier-free, all-register h1 fragments ----------------
__global__ __launch_bounds__(256, 2) void edge_mlp_kernel(
    const bf16_t* __restrict__ P, const bf16_t* __restrict__ Q, const int* __restrict__ idx,
    const bf16_t* __restrict__ W2T, const float* __restrict__ b2,
    bf16_t* __restrict__ xout, float* __restrict__ pooled, int poolOff)
{
  const int b = blockIdx.y;
  const size_t bNP = (size_t)b * NP;
  const int t = threadIdx.x;
  const int lane = t & 63, w = t >> 6, quad = lane >> 4, l16 = lane & 15;
  const int pbase = blockIdx.x * 64 + w * 16;
  const bf16_t* __restrict__ Wb = W2T + (size_t)l16 * HD + quad * 8;
#define LDB(ks, ct) const bf16x8 B##ks##ct = *(const bf16x8*)&Wb[ct*16*HD + ks*32];
  LDB(0,0) LDB(0,1) LDB(0,2) LDB(0,3) LDB(0,4) LDB(0,5) LDB(0,6) LDB(0,7)
  LDB(1,0) LDB(1,1) LDB(1,2) LDB(1,3) LDB(1,4) LDB(1,5) LDB(1,6) LDB(1,7)
#undef LDB
  const float bv0 = b2[  0 + l16], bv1 = b2[ 16 + l16], bv2 = b2[ 32 + l16], bv3 = b2[ 48 + l16];
  const float bv4 = b2[ 64 + l16], bv5 = b2[ 80 + l16], bv6 = b2[ 96 + l16], bv7 = b2[112 + l16];
  float pa0=0.f, pa1=0.f, pa2=0.f, pa3=0.f, pa4=0.f, pa5=0.f, pa6=0.f, pa7=0.f;
  const f32x4 z = {0.f, 0.f, 0.f, 0.f};
  for (int it = 0; it < 8; ++it) {
    const int ip = pbase + it*2 + (l16 >> 3);
    const int j = idx[(bNP + ip)*8 + (l16 & 7)];
    const bf16_t* Qr = Q + (bNP + (unsigned)j)*HD + quad*8;
    const bf16_t* Pr = P + (bNP + ip)*HD + quad*8;
    bf16x8 q0 = *(const bf16x8*)(Qr     );
    bf16x8 q1 = *(const bf16x8*)(Qr + 32);
    bf16x8 q2 = *(const bf16x8*)(Qr + 64);
    bf16x8 q3 = *(const bf16x8*)(Qr + 96);
    bf16x8 p0 = *(const bf16x8*)(Pr     );
    bf16x8 p1 = *(const bf16x8*)(Pr + 32);
    bf16x8 p2 = *(const bf16x8*)(Pr + 64);
    bf16x8 p3 = *(const bf16x8*)(Pr + 96);
    bf16x8 af0, af1, af2, af3;
#pragma unroll
    for (int k = 0; k < 8; ++k) {
      af0[k] = (bf16_t)fmaxf((float)p0[k] + (float)q0[k], 0.f);
      af1[k] = (bf16_t)fmaxf((float)p1[k] + (float)q1[k], 0.f);
      af2[k] = (bf16_t)fmaxf((float)p2[k] + (float)q2[k], 0.f);
      af3[k] = (bf16_t)fmaxf((float)p3[k] + (float)q3[k], 0.f);
    }
    f32x4 ac0=z, ac1=z, ac2=z, ac3=z, ac4=z, ac5=z, ac6=z, ac7=z;
    ac0 = __builtin_amdgcn_mfma_f32_16x16x32_bf16(af0, B00, ac0, 0,0,0);
    ac1 = __builtin_amdgcn_mfma_f32_16x16x32_bf16(af0, B01, ac1, 0,0,0);
    ac2 = __builtin_amdgcn_mfma_f32_16x16x32_bf16(af0, B02, ac2, 0,0,0);
    ac3 = __builtin_amdgcn_mfma_f32_16x16x32_bf16(af0, B03, ac3, 0,0,0);
    ac4 = __builtin_amdgcn_mfma_f32_16x16x32_bf16(af0, B04, ac4, 0,0,0);
    ac5 = __builtin_amdgcn_mfma_f32_16x16x32_bf16(af0, B05, ac5, 0,0,0);
    ac6 = __builtin_amdgcn_mfma_f32_16x16x32_bf16(af0, B06, ac6, 0,0,0);
    ac7 = __builtin_amdgcn_mfma_f32_16x16x32_bf16(af0, B07, ac7, 0,0,0);
    ac0 = __builtin_amdgcn_mfma_f32_16x16x32_bf16(af1, B10, ac0, 0,0,0);
    ac1 = __builtin_amdgcn_mfma_f32_16x16x32_bf16(af1, B11, ac1, 0,0,0);
    ac2 = __builtin_amdgcn_mfma_f32_16x16x32_bf16(af1, B12, ac2, 0,0,0);
    ac3 = __builtin_amdgcn_mfma_f32_16x16x32_bf16(af1, B13, ac3, 0,0,0);
    ac4 = __builtin_amdgcn_mfma_f32_16x16x32_bf16(af1, B14, ac4, 0,0,0);
    ac5 = __builtin_amdgcn_mfma_f32_16x16x32_bf16(af1, B15, ac5, 0,0,0);
    ac6 = __builtin_amdgcn_mfma_f32_16x16x32_bf16(af1, B16, ac6, 0,0,0);
    ac7 = __builtin_amdgcn_mfma_f32_16x16x32_bf16(af1, B17, ac7, 0,0,0);
#define MM2(ct, accv) { \
    bf16x8 b2f = *(const bf16x8*)&Wb[ct*16*HD + 2*32]; \
    accv = __builtin_amdgcn_mfma_f32_16x16x32_bf16(af2, b2f, accv, 0,0,0); \
    bf16x8 b3f = *(const bf16x8*)&Wb[ct*16*HD + 3*32]; \
    accv = __builtin_amdgcn_mfma_f32_16x16x32_bf16(af3, b3f, accv, 0,0,0); }
    MM2(0, ac0) MM2(1, ac1) MM2(2, ac2) MM2(3, ac3)
    MM2(4, ac4) MM2(5, ac5) MM2(6, ac6) MM2(7, ac7)
#undef MM2
    const int ipt = pbase + it*2 + (quad >> 1);
    bf16_t* xr = xout + (bNP + ipt)*HD + l16;
#define EPI(ct, accv, bvv, pav) { \
    float s = fmaxf(accv[0]+bvv,0.f) + fmaxf(accv[1]+bvv,0.f) \
            + fmaxf(accv[2]+bvv,0.f) + fmaxf(accv[3]+bvv,0.f); \
    s += __shfl_xor(s, 16); \
    if ((quad & 1) == 0) xr[ct*16] = (bf16_t)(s * 0.125f); \
    pav += s + __shfl_xor(s, 32); }
    EPI(0, ac0, bv0, pa0) EPI(1, ac1, bv1, pa1) EPI(2, ac2, bv2, pa2) EPI(3, ac3, bv3, pa3)
    EPI(4, ac4, bv4, pa4) EPI(5, ac5, bv5, pa5) EPI(6, ac6, bv6, pa6) EPI(7, ac7, bv7, pa7)
#undef EPI
  }
  if (quad == 0) {
    float* pr = pooled + b*384 + poolOff + l16;
    atomicAdd(pr +   0, pa0 * 0.125f);
    atomicAdd(pr +  16, pa1 * 0.125f);
    atomicAdd(pr +  32, pa2 * 0.125f);
    atomicAdd(pr +  48, pa3 * 0.125f);
    atomicAdd(pr +  64, pa4 * 0.125f);
    atomicAdd(pr +  80, pa5 * 0.125f);
    atomicAdd(pr +  96, pa6 * 0.125f);
    atomicAdd(pr + 112, pa7 * 0.125f);
  }
}

// ---------------- final pooled MLP ----------------
__global__ __launch_bounds__(128) void final_mlp_kernel(
    const float* __restrict__ pooled, const float* __restrict__ W1, const float* __restrict__ b1v,
    const float* __restrict__ W2, const float* __restrict__ b2v, float* __restrict__ out)
{
  __shared__ float hb[128];
  int b = blockIdx.x, g = threadIdx.x;
  float h = b1v[g];
  const float inv = 1.0f / (float)NP;
  for (int c = 0; c < 384; ++c) h += pooled[b*384 + c] * inv * W1[c*128 + g];
  hb[g] = fmaxf(h, 0.f);
  __syncthreads();
  if (g < 2) {
    float o = b2v[g];
    for (int k2 = 0; k2 < 128; ++k2) o += hb[k2] * W2[k2*2 + g];
    out[b*2 + g] = o;
  }
}

extern "C" void kernel_launch(void* const* d_in, const int* in_sizes, int n_in,
                              void* d_out, int out_size, void* d_ws, size_t ws_size,
                              hipStream_t stream) {
  (void)in_sizes; (void)n_in; (void)out_size; (void)ws_size;
  const float* x    = (const float*)d_in[0];
  const float* c1W1 = (const float*)d_in[1];
  const float* c1b1 = (const float*)d_in[2];
  const float* c1W2 = (const float*)d_in[3];
  const float* c1b2 = (const float*)d_in[4];
  const float* c2W1 = (const float*)d_in[5];
  const float* c2b1 = (const float*)d_in[6];
  const float* c2W2 = (const float*)d_in[7];
  const float* c2b2 = (const float*)d_in[8];
  const float* c3W1 = (const float*)d_in[9];
  const float* c3b1 = (const float*)d_in[10];
  const float* c3W2 = (const float*)d_in[11];
  const float* c3b2 = (const float*)d_in[12];
  const float* mW1  = (const float*)d_in[13];
  const float* mb1  = (const float*)d_in[14];
  const float* mW2  = (const float*)d_in[15];
  const float* mb2  = (const float*)d_in[16];

  char* wsp = (char*)d_ws;
  auto carve = [&](size_t bytes) -> void* {
    void* p = (void*)wsp; wsp += (bytes + 255) & ~(size_t)255; return p;
  };
  bf16_t* x1b  = (bf16_t*)carve((size_t)NB*NP*HD*2);
  bf16_t* x2b  = (bf16_t*)carve((size_t)NB*NP*HD*2);
  bf16_t* x3b  = (bf16_t*)carve((size_t)NB*NP*HD*2);
  bf16_t* Pbuf = (bf16_t*)carve((size_t)NB*NP*HD*2);
  bf16_t* Qbuf = (bf16_t*)carve((size_t)NB*NP*HD*2);
  float*  sqb  = (float*)carve((size_t)NB*NP*4);
  int*    idxb = (int*)carve((size_t)NB*NP*8*4);
  unsigned* pkw = (unsigned*)carve((size_t)NB*NP*JSEG*8*4);
  bf16_t* W2T1 = (bf16_t*)carve(128*128*2);
  bf16_t* WpT2 = (bf16_t*)carve(128*128*2);
  bf16_t* WqT2 = (bf16_t*)carve(128*128*2);
  bf16_t* W2T2 = (bf16_t*)carve(128*128*2);
  bf16_t* WpT3 = (bf16_t*)carve(128*128*2);
  bf16_t* WqT3 = (bf16_t*)carve(128*128*2);
  bf16_t* W2T3 = (bf16_t*)carve(128*128*2);
  float*  pooled = (float*)carve((size_t)NB*384*4);

  wprep_kernel<<<449, 256, 0, stream>>>(c1W2, c2W1, c2W2, c3W1, c3W2,
                                        W2T1, WpT2, WqT2, W2T2, WpT3, WqT3, W2T3, pooled);
  // layer 1
  pq1_kernel<<<4096, 256, 0, stream>>>(x, c1W1, c1b1, Pbuf, Qbuf);
  knn1_kernel<<<dim3(NP/32, NB), 256, 0, stream>>>(x, idxb);
  edge_mlp_kernel<<<dim3(NP/64, NB), 256, 0, stream>>>(Pbuf, Qbuf, idxb, W2T1, c1b2, x1b, pooled, 0);
  // layer 2
  pq_gemm_kernel<<<dim3(NB*NP/128, 2), 256, 0, stream>>>(x1b, WpT2, WqT2, c2b1, Pbuf, Qbuf, sqb);
  knn_big_kernel<<<dim3(NP/128, NB, JSEG), 512, 0, stream>>>(x1b, sqb, pkw);
  knn_merge_kernel<<<NB*NP/256, 256, 0, stream>>>(pkw, idxb);
  edge_mlp_kernel<<<dim3(NP/64, NB), 256, 0, stream>>>(Pbuf, Qbuf, idxb, W2T2, c2b2, x2b, pooled, 128);
  // layer 3
  pq_gemm_kernel<<<dim3(NB*NP/128, 2), 256, 0, stream>>>(x2b, WpT3, WqT3, c3b1, Pbuf, Qbuf, sqb);
  knn_big_kernel<<<dim3(NP/128, NB, JSEG), 512, 0, stream>>>(x2b, sqb, pkw);
  knn_merge_kernel<<<NB*NP/256, 256, 0, stream>>>(pkw, idxb);
  edge_mlp_kernel<<<dim3(NP/64, NB), 256, 0, stream>>>(Pbuf, Qbuf, idxb, W2T3, c3b2, x3b, pooled, 256);
  // head
  final_mlp_kernel<<<NB, 128, 0, stream>>>(pooled, mW1, mb1, mW2, mb2, (float*)d_out);
}